// Round 1
// baseline (5697.223 us; speedup 1.0000x reference)
//
#include <hip/hip_runtime.h>

#define D 256
#define ROWS_PER_BLOCK 32

// Kernel 1: agg = feat  (init d_out with feat so scatter accumulates (agg+feat))
__global__ __launch_bounds__(256) void gc_copy(const float* __restrict__ feat,
                                               float* __restrict__ agg,
                                               long n4) {
    long i = (long)blockIdx.x * blockDim.x + threadIdx.x;
    if (i < n4) {
        reinterpret_cast<float4*>(agg)[i] =
            reinterpret_cast<const float4*>(feat)[i];
    }
}

// Kernel 2: for each edge e: agg[dst[e]] += feat[src[e]]  (one wave per edge)
__global__ __launch_bounds__(256) void gc_scatter(const float* __restrict__ feat,
                                                  const int* __restrict__ src,
                                                  const int* __restrict__ dst,
                                                  float* __restrict__ agg,
                                                  int n_edges) {
    int wave = (int)((blockIdx.x * (long)blockDim.x + threadIdx.x) >> 6);
    int lane = threadIdx.x & 63;
    if (wave >= n_edges) return;
    int s = src[wave];
    int d = dst[wave];
    const float4 v =
        reinterpret_cast<const float4*>(feat + (size_t)s * D)[lane];
    float* p = agg + (size_t)d * D + (size_t)lane * 4;
    atomicAdd(p + 0, v.x);
    atomicAdd(p + 1, v.y);
    atomicAdd(p + 2, v.z);
    atomicAdd(p + 3, v.w);
}

// Kernel 3: in-place  out[r] = relu(out[r] @ W)  for ROWS_PER_BLOCK rows/block.
// 256 threads; thread c owns output column c for all 32 rows.
__global__ __launch_bounds__(256) void gc_gemm_relu(const float* __restrict__ W,
                                                    float* __restrict__ out,
                                                    int n_rows) {
    __shared__ float s_a[ROWS_PER_BLOCK][D];  // 32 KB
    const int row0 = blockIdx.x * ROWS_PER_BLOCK;
    const int c = threadIdx.x;

    // Stage the block's rows into LDS (vectorized float4, fully coalesced).
    {
        const float4* gsrc = reinterpret_cast<const float4*>(out + (size_t)row0 * D);
        float4* ldst = reinterpret_cast<float4*>(&s_a[0][0]);
        #pragma unroll
        for (int i = 0; i < (ROWS_PER_BLOCK * D / 4) / 256; ++i) {
            ldst[threadIdx.x + i * 256] = gsrc[threadIdx.x + i * 256];
        }
    }
    __syncthreads();

    float acc[ROWS_PER_BLOCK];
    #pragma unroll
    for (int r = 0; r < ROWS_PER_BLOCK; ++r) acc[r] = 0.0f;

    // k-loop: coalesced W row load (one float per thread), LDS broadcasts for A.
    #pragma unroll 4
    for (int k = 0; k < D; ++k) {
        float w = W[(size_t)k * D + c];
        #pragma unroll
        for (int r = 0; r < ROWS_PER_BLOCK; ++r) {
            acc[r] += s_a[r][k] * w;
        }
    }

    // Write back (same rows this block staged — in-place safe, no 2nd barrier
    // needed since all LDS reads above are from this block's own staged data).
    #pragma unroll
    for (int r = 0; r < ROWS_PER_BLOCK; ++r) {
        int row = row0 + r;
        if (row < n_rows) {
            out[(size_t)row * D + c] = fmaxf(acc[r], 0.0f);
        }
    }
}

extern "C" void kernel_launch(void* const* d_in, const int* in_sizes, int n_in,
                              void* d_out, int out_size, void* d_ws, size_t ws_size,
                              hipStream_t stream) {
    const float* feat = (const float*)d_in[0];
    const float* W    = (const float*)d_in[1];
    const int*   src  = (const int*)d_in[2];
    const int*   dst  = (const int*)d_in[3];
    float* out = (float*)d_out;

    const int n_nodes = in_sizes[0] / D;     // 100000
    const int n_edges = in_sizes[2];         // 1600000

    // 1) out = feat
    {
        long n4 = (long)n_nodes * D / 4;
        int blocks = (int)((n4 + 255) / 256);
        gc_copy<<<blocks, 256, 0, stream>>>(feat, out, n4);
    }

    // 2) scatter-add: one wave (64 lanes) per edge, 4 edges per 256-thr block
    {
        int blocks = (n_edges + 3) / 4;
        gc_scatter<<<blocks, 256, 0, stream>>>(feat, src, dst, out, n_edges);
    }

    // 3) in-place GEMM + ReLU
    {
        int blocks = (n_nodes + ROWS_PER_BLOCK - 1) / ROWS_PER_BLOCK;
        gc_gemm_relu<<<blocks, 256, 0, stream>>>(W, out, n_nodes);
    }
}

// Round 2
// 1000.799 us; speedup vs baseline: 5.6927x; 5.6927x over previous
//
#include <hip/hip_runtime.h>

#define D 256
#define ROWS_PER_BLOCK 32
#define SCAN_THREADS 1024

// ---------- CSR build ----------

__global__ void k_zero(int* __restrict__ p, int n) {
    int i = blockIdx.x * blockDim.x + threadIdx.x;
    if (i < n) p[i] = 0;
}

__global__ void k_hist(const int* __restrict__ dst, int* __restrict__ counts, int E) {
    for (int e = blockIdx.x * blockDim.x + threadIdx.x; e < E;
         e += gridDim.x * blockDim.x)
        atomicAdd(&counts[dst[e]], 1);
}

// Single-workgroup exclusive scan of counts[0..N) -> offsets[0..N], also
// initializes cursor = offsets (for the fill pass).
__global__ __launch_bounds__(SCAN_THREADS) void k_scan(const int* __restrict__ counts,
                                                       int* __restrict__ offsets,
                                                       int* __restrict__ cursor,
                                                       int N) {
    __shared__ int s[SCAN_THREADS];
    const int t = threadIdx.x;
    const int chunk = (N + SCAN_THREADS - 1) / SCAN_THREADS;
    const int lo = t * chunk;
    const int hi = min(N, lo + chunk);
    int local = 0;
    for (int i = lo; i < hi; ++i) local += counts[i];
    s[t] = local;
    __syncthreads();
    // Hillis-Steele inclusive scan over 1024 partials
    for (int str = 1; str < SCAN_THREADS; str <<= 1) {
        int v = (t >= str) ? s[t - str] : 0;
        __syncthreads();
        s[t] += v;
        __syncthreads();
    }
    int run = s[t] - local;  // exclusive base for this thread's chunk
    for (int i = lo; i < hi; ++i) {
        offsets[i] = run;
        cursor[i] = run;
        run += counts[i];
    }
    if (t == SCAN_THREADS - 1) offsets[N] = s[SCAN_THREADS - 1];
}

__global__ void k_fill(const int* __restrict__ src, const int* __restrict__ dst,
                       int* __restrict__ cursor, int* __restrict__ buckets, int E) {
    for (int e = blockIdx.x * blockDim.x + threadIdx.x; e < E;
         e += gridDim.x * blockDim.x) {
        int pos = atomicAdd(&cursor[dst[e]], 1);
        buckets[pos] = src[e];
    }
}

// ---------- gather: out[n] = feat[n] + sum_{s in in(n)} feat[s] ----------
// One wave (64 lanes) per node; lane holds float4 (16B) of the 1KB row.
__global__ __launch_bounds__(256) void k_gather(const float* __restrict__ feat,
                                                const int* __restrict__ offsets,
                                                const int* __restrict__ buckets,
                                                float* __restrict__ out, int N) {
    int wave = (int)((blockIdx.x * (long)blockDim.x + threadIdx.x) >> 6);
    int lane = threadIdx.x & 63;
    if (wave >= N) return;
    const int off = offsets[wave];
    const int end = offsets[wave + 1];
    float4 acc = reinterpret_cast<const float4*>(feat + (size_t)wave * D)[lane];
    for (int j = off; j < end; ++j) {
        int s = buckets[j];  // same addr across wave -> broadcast
        float4 v = reinterpret_cast<const float4*>(feat + (size_t)s * D)[lane];
        acc.x += v.x; acc.y += v.y; acc.z += v.z; acc.w += v.w;
    }
    reinterpret_cast<float4*>(out + (size_t)wave * D)[lane] = acc;
}

// ---------- fallback scatter path (if ws too small) ----------

__global__ __launch_bounds__(256) void gc_copy(const float* __restrict__ feat,
                                               float* __restrict__ agg, long n4) {
    long i = (long)blockIdx.x * blockDim.x + threadIdx.x;
    if (i < n4)
        reinterpret_cast<float4*>(agg)[i] = reinterpret_cast<const float4*>(feat)[i];
}

__global__ __launch_bounds__(256) void gc_scatter(const float* __restrict__ feat,
                                                  const int* __restrict__ src,
                                                  const int* __restrict__ dst,
                                                  float* __restrict__ agg, int n_edges) {
    int wave = (int)((blockIdx.x * (long)blockDim.x + threadIdx.x) >> 6);
    int lane = threadIdx.x & 63;
    if (wave >= n_edges) return;
    int s = src[wave];
    int d = dst[wave];
    const float4 v = reinterpret_cast<const float4*>(feat + (size_t)s * D)[lane];
    float* p = agg + (size_t)d * D + (size_t)lane * 4;
    atomicAdd(p + 0, v.x);
    atomicAdd(p + 1, v.y);
    atomicAdd(p + 2, v.z);
    atomicAdd(p + 3, v.w);
}

// ---------- GEMM + ReLU (in-place on out) ----------

__global__ __launch_bounds__(256) void gc_gemm_relu(const float* __restrict__ W,
                                                    float* __restrict__ out, int n_rows) {
    __shared__ float s_a[ROWS_PER_BLOCK][D];  // 32 KB
    const int row0 = blockIdx.x * ROWS_PER_BLOCK;
    const int c = threadIdx.x;

    {
        const float4* gsrc = reinterpret_cast<const float4*>(out + (size_t)row0 * D);
        float4* ldst = reinterpret_cast<float4*>(&s_a[0][0]);
        #pragma unroll
        for (int i = 0; i < (ROWS_PER_BLOCK * D / 4) / 256; ++i)
            ldst[threadIdx.x + i * 256] = gsrc[threadIdx.x + i * 256];
    }
    __syncthreads();

    float acc[ROWS_PER_BLOCK];
    #pragma unroll
    for (int r = 0; r < ROWS_PER_BLOCK; ++r) acc[r] = 0.0f;

    #pragma unroll 4
    for (int k = 0; k < D; ++k) {
        float w = W[(size_t)k * D + c];
        #pragma unroll
        for (int r = 0; r < ROWS_PER_BLOCK; ++r) acc[r] += s_a[r][k] * w;
    }

    #pragma unroll
    for (int r = 0; r < ROWS_PER_BLOCK; ++r) {
        int row = row0 + r;
        if (row < n_rows) out[(size_t)row * D + c] = fmaxf(acc[r], 0.0f);
    }
}

extern "C" void kernel_launch(void* const* d_in, const int* in_sizes, int n_in,
                              void* d_out, int out_size, void* d_ws, size_t ws_size,
                              hipStream_t stream) {
    const float* feat = (const float*)d_in[0];
    const float* W    = (const float*)d_in[1];
    const int*   src  = (const int*)d_in[2];
    const int*   dst  = (const int*)d_in[3];
    float* out = (float*)d_out;

    const int N = in_sizes[0] / D;   // 100000 nodes
    const int E = in_sizes[2];       // 1600000 edges

    // ws layout: counts[N] | offsets[N+1] | cursor[N] | buckets[E]
    const size_t need = ((size_t)3 * N + 1 + (size_t)E) * sizeof(int);

    if (ws_size >= need) {
        int* counts  = (int*)d_ws;
        int* offsets = counts + N;
        int* cursor  = offsets + N + 1;
        int* buckets = cursor + N;

        k_zero<<<(N + 255) / 256, 256, 0, stream>>>(counts, N);
        k_hist<<<2048, 256, 0, stream>>>(dst, counts, E);
        k_scan<<<1, SCAN_THREADS, 0, stream>>>(counts, offsets, cursor, N);
        k_fill<<<2048, 256, 0, stream>>>(src, dst, cursor, buckets, E);
        // out = feat + segment_sum(feat[src], dst)
        k_gather<<<(N + 3) / 4, 256, 0, stream>>>(feat, offsets, buckets, out, N);
    } else {
        // fallback: atomic scatter
        long n4 = (long)N * D / 4;
        gc_copy<<<(int)((n4 + 255) / 256), 256, 0, stream>>>(feat, out, n4);
        gc_scatter<<<(E + 3) / 4, 256, 0, stream>>>(feat, src, dst, out, E);
    }

    // in-place GEMM + ReLU
    gc_gemm_relu<<<(N + ROWS_PER_BLOCK - 1) / ROWS_PER_BLOCK, 256, 0, stream>>>(W, out, N);
}

// Round 3
// 850.930 us; speedup vs baseline: 6.6953x; 1.1761x over previous
//
#include <hip/hip_runtime.h>

#define D 256
#define SCAN_THREADS 1024

// GEMM tiling
#define BM 64
#define KT 32

// ---------- CSR build ----------

__global__ void k_zero(int* __restrict__ p, int n) {
    int i = blockIdx.x * blockDim.x + threadIdx.x;
    if (i < n) p[i] = 0;
}

__global__ void k_hist(const int* __restrict__ dst, int* __restrict__ counts, int E) {
    for (int e = blockIdx.x * blockDim.x + threadIdx.x; e < E;
         e += gridDim.x * blockDim.x)
        atomicAdd(&counts[dst[e]], 1);
}

__global__ __launch_bounds__(SCAN_THREADS) void k_scan(const int* __restrict__ counts,
                                                       int* __restrict__ offsets,
                                                       int* __restrict__ cursor,
                                                       int N) {
    __shared__ int s[SCAN_THREADS];
    const int t = threadIdx.x;
    const int chunk = (N + SCAN_THREADS - 1) / SCAN_THREADS;
    const int lo = t * chunk;
    const int hi = min(N, lo + chunk);
    int local = 0;
    for (int i = lo; i < hi; ++i) local += counts[i];
    s[t] = local;
    __syncthreads();
    for (int str = 1; str < SCAN_THREADS; str <<= 1) {
        int v = (t >= str) ? s[t - str] : 0;
        __syncthreads();
        s[t] += v;
        __syncthreads();
    }
    int run = s[t] - local;
    for (int i = lo; i < hi; ++i) {
        offsets[i] = run;
        cursor[i] = run;
        run += counts[i];
    }
    if (t == SCAN_THREADS - 1) offsets[N] = s[SCAN_THREADS - 1];
}

__global__ void k_fill(const int* __restrict__ src, const int* __restrict__ dst,
                       int* __restrict__ cursor, int* __restrict__ buckets, int E) {
    for (int e = blockIdx.x * blockDim.x + threadIdx.x; e < E;
         e += gridDim.x * blockDim.x) {
        int pos = atomicAdd(&cursor[dst[e]], 1);
        buckets[pos] = src[e];
    }
}

// ---------- gather: out[n] = feat[n] + sum_{s in in(n)} feat[s] ----------
// One wave per node; 4-wide unrolled so 4 row-loads are in flight.
__global__ __launch_bounds__(256) void k_gather(const float* __restrict__ feat,
                                                const int* __restrict__ offsets,
                                                const int* __restrict__ buckets,
                                                float* __restrict__ out, int N) {
    int wave = (int)((blockIdx.x * (long)blockDim.x + threadIdx.x) >> 6);
    int lane = threadIdx.x & 63;
    if (wave >= N) return;
    const int off = offsets[wave];
    const int end = offsets[wave + 1];
    float4 acc = reinterpret_cast<const float4*>(feat + (size_t)wave * D)[lane];
    int j = off;
    for (; j + 4 <= end; j += 4) {
        int s0 = buckets[j + 0];
        int s1 = buckets[j + 1];
        int s2 = buckets[j + 2];
        int s3 = buckets[j + 3];
        float4 v0 = reinterpret_cast<const float4*>(feat + (size_t)s0 * D)[lane];
        float4 v1 = reinterpret_cast<const float4*>(feat + (size_t)s1 * D)[lane];
        float4 v2 = reinterpret_cast<const float4*>(feat + (size_t)s2 * D)[lane];
        float4 v3 = reinterpret_cast<const float4*>(feat + (size_t)s3 * D)[lane];
        acc.x += v0.x + v1.x + v2.x + v3.x;
        acc.y += v0.y + v1.y + v2.y + v3.y;
        acc.z += v0.z + v1.z + v2.z + v3.z;
        acc.w += v0.w + v1.w + v2.w + v3.w;
    }
    for (; j < end; ++j) {
        int s = buckets[j];
        float4 v = reinterpret_cast<const float4*>(feat + (size_t)s * D)[lane];
        acc.x += v.x; acc.y += v.y; acc.z += v.z; acc.w += v.w;
    }
    reinterpret_cast<float4*>(out + (size_t)wave * D)[lane] = acc;
}

// ---------- fallback scatter path ----------

__global__ __launch_bounds__(256) void gc_copy(const float* __restrict__ feat,
                                               float* __restrict__ agg, long n4) {
    long i = (long)blockIdx.x * blockDim.x + threadIdx.x;
    if (i < n4)
        reinterpret_cast<float4*>(agg)[i] = reinterpret_cast<const float4*>(feat)[i];
}

__global__ __launch_bounds__(256) void gc_scatter(const float* __restrict__ feat,
                                                  const int* __restrict__ src,
                                                  const int* __restrict__ dst,
                                                  float* __restrict__ agg, int n_edges) {
    int wave = (int)((blockIdx.x * (long)blockDim.x + threadIdx.x) >> 6);
    int lane = threadIdx.x & 63;
    if (wave >= n_edges) return;
    int s = src[wave];
    int d = dst[wave];
    const float4 v = reinterpret_cast<const float4*>(feat + (size_t)s * D)[lane];
    float* p = agg + (size_t)d * D + (size_t)lane * 4;
    atomicAdd(p + 0, v.x);
    atomicAdd(p + 1, v.y);
    atomicAdd(p + 2, v.z);
    atomicAdd(p + 3, v.w);
}

// ---------- register-tiled GEMM + ReLU, in-place on out ----------
// BM=64 rows x BN=256 (full width -> in-place safe). 256 threads.
// Thread (rg = t>>4, cg = t&15) computes rows rg*4..+3, cols cg*4 + 64j (j=0..3).
// A,W tiles staged via global_load_lds (width 16).
__device__ inline void gload16(const float* g, const float* lds) {
    __builtin_amdgcn_global_load_lds(
        (const __attribute__((address_space(1))) void*)g,
        (__attribute__((address_space(3))) void*)lds, 16, 0, 0);
}

__global__ __launch_bounds__(256) void gemm_relu(const float* __restrict__ W,
                                                 float* __restrict__ out, int n_rows) {
    __shared__ float s_a[BM][KT];   // 8 KB
    __shared__ float s_w[KT][D];    // 32 KB
    const int t = threadIdx.x;
    const int row0 = blockIdx.x * BM;
    const int rg = t >> 4;          // 0..15
    const int cg = t & 15;          // 0..15
    const int wv = t >> 6;          // wave 0..3
    const int ln = t & 63;

    float4 acc[4][4];
    #pragma unroll
    for (int i = 0; i < 4; ++i)
        #pragma unroll
        for (int j = 0; j < 4; ++j) acc[i][j] = make_float4(0.f, 0.f, 0.f, 0.f);

    const int c0 = cg * 4;
    const int r0 = rg * 4;

    for (int kt = 0; kt < D; kt += KT) {
        // --- stage W tile: rows kt..kt+31, contiguous 32KB; 32 chunks of 1KB.
        // wave wv stages chunks 8*wv .. 8*wv+7
        #pragma unroll
        for (int q8 = 0; q8 < 8; ++q8) {
            int q = wv * 8 + q8;  // W row kt+q
            gload16(W + (size_t)(kt + q) * D + ln * 4, &s_w[q][0]);
        }
        // --- stage A tile: rows row0..row0+63, cols kt..kt+31; 8 chunks of 1KB
        // (8 rows each). wave wv stages chunks 2*wv, 2*wv+1.
        #pragma unroll
        for (int q2 = 0; q2 < 2; ++q2) {
            int q = wv * 2 + q2;
            int grow = row0 + q * 8 + (ln >> 3);
            if (grow > n_rows - 1) grow = n_rows - 1;  // clamp (no OOB read)
            gload16(out + (size_t)grow * D + kt + (ln & 7) * 4, &s_a[q * 8][0]);
        }
        __syncthreads();  // compiler drains vmcnt before s_barrier

        #pragma unroll 4
        for (int k = 0; k < KT; ++k) {
            float a0 = s_a[r0 + 0][k];
            float a1 = s_a[r0 + 1][k];
            float a2 = s_a[r0 + 2][k];
            float a3 = s_a[r0 + 3][k];
            #pragma unroll
            for (int j = 0; j < 4; ++j) {
                float4 w = *reinterpret_cast<const float4*>(&s_w[k][c0 + j * 64]);
                acc[0][j].x += a0 * w.x; acc[0][j].y += a0 * w.y;
                acc[0][j].z += a0 * w.z; acc[0][j].w += a0 * w.w;
                acc[1][j].x += a1 * w.x; acc[1][j].y += a1 * w.y;
                acc[1][j].z += a1 * w.z; acc[1][j].w += a1 * w.w;
                acc[2][j].x += a2 * w.x; acc[2][j].y += a2 * w.y;
                acc[2][j].z += a2 * w.z; acc[2][j].w += a2 * w.w;
                acc[3][j].x += a3 * w.x; acc[3][j].y += a3 * w.y;
                acc[3][j].z += a3 * w.z; acc[3][j].w += a3 * w.w;
            }
        }
        __syncthreads();
    }

    #pragma unroll
    for (int i = 0; i < 4; ++i) {
        int row = row0 + r0 + i;
        if (row < n_rows) {
            #pragma unroll
            for (int j = 0; j < 4; ++j) {
                float4 v = acc[i][j];
                v.x = fmaxf(v.x, 0.f); v.y = fmaxf(v.y, 0.f);
                v.z = fmaxf(v.z, 0.f); v.w = fmaxf(v.w, 0.f);
                *reinterpret_cast<float4*>(&out[(size_t)row * D + c0 + j * 64]) = v;
            }
        }
    }
}

extern "C" void kernel_launch(void* const* d_in, const int* in_sizes, int n_in,
                              void* d_out, int out_size, void* d_ws, size_t ws_size,
                              hipStream_t stream) {
    const float* feat = (const float*)d_in[0];
    const float* W    = (const float*)d_in[1];
    const int*   src  = (const int*)d_in[2];
    const int*   dst  = (const int*)d_in[3];
    float* out = (float*)d_out;

    const int N = in_sizes[0] / D;   // 100000 nodes
    const int E = in_sizes[2];       // 1600000 edges

    const size_t need = ((size_t)3 * N + 1 + (size_t)E) * sizeof(int);

    if (ws_size >= need) {
        int* counts  = (int*)d_ws;
        int* offsets = counts + N;
        int* cursor  = offsets + N + 1;
        int* buckets = cursor + N;

        k_zero<<<(N + 255) / 256, 256, 0, stream>>>(counts, N);
        k_hist<<<2048, 256, 0, stream>>>(dst, counts, E);
        k_scan<<<1, SCAN_THREADS, 0, stream>>>(counts, offsets, cursor, N);
        k_fill<<<2048, 256, 0, stream>>>(src, dst, cursor, buckets, E);
        k_gather<<<(N + 3) / 4, 256, 0, stream>>>(feat, offsets, buckets, out, N);
    } else {
        long n4 = (long)N * D / 4;
        gc_copy<<<(int)((n4 + 255) / 256), 256, 0, stream>>>(feat, out, n4);
        gc_scatter<<<(E + 3) / 4, 256, 0, stream>>>(feat, src, dst, out, E);
    }

    gemm_relu<<<(N + BM - 1) / BM, 256, 0, stream>>>(W, out, N);
}

// Round 4
// 616.828 us; speedup vs baseline: 9.2363x; 1.3795x over previous
//
#include <hip/hip_runtime.h>

#define D 256
#define SCAN_THREADS 1024
#define CAP 48
#define MAXOVF 4096

// GEMM tiling
#define BM 64
#define GKT 32
#define APAD 4  // s_aT row pad (words): stride 68 floats = 272B, 16B-aligned

// ================= capacity-bucket build (primary path) =================

__global__ void k_zero(int* __restrict__ p, int n) {
    int i = blockIdx.x * blockDim.x + threadIdx.x;
    if (i < n) p[i] = 0;
}

__global__ void k_fillcap(const int* __restrict__ src, const int* __restrict__ dst,
                          int* __restrict__ counts, int* __restrict__ buckets,
                          int* __restrict__ ovf, int* __restrict__ ovf_cnt, int E) {
    for (int e = blockIdx.x * blockDim.x + threadIdx.x; e < E;
         e += gridDim.x * blockDim.x) {
        int d = dst[e];
        int pos = atomicAdd(&counts[d], 1);
        if (pos < CAP) {
            buckets[(size_t)d * CAP + pos] = src[e];
        } else {
            int o = atomicAdd(ovf_cnt, 1);
            if (o < MAXOVF) {
                ovf[2 * o + 0] = src[e];
                ovf[2 * o + 1] = d;
            }
        }
    }
}

// out[n] = feat[n] + sum of bucketed src rows. One wave per node, 8-deep MLP.
__global__ __launch_bounds__(256) void k_gather_cap(const float* __restrict__ feat,
                                                    const int* __restrict__ counts,
                                                    const int* __restrict__ buckets,
                                                    float* __restrict__ out, int N) {
    int wave = (int)((blockIdx.x * (long)blockDim.x + threadIdx.x) >> 6);
    int lane = threadIdx.x & 63;
    if (wave >= N) return;
    int cnt = counts[wave];
    if (cnt > CAP) cnt = CAP;
    const int* bk = buckets + (size_t)wave * CAP;
    float4 acc = reinterpret_cast<const float4*>(feat + (size_t)wave * D)[lane];
    int j = 0;
    for (; j + 8 <= cnt; j += 8) {
        int s[8];
        #pragma unroll
        for (int q = 0; q < 8; ++q) s[q] = bk[j + q];
        float4 v[8];
        #pragma unroll
        for (int q = 0; q < 8; ++q)
            v[q] = reinterpret_cast<const float4*>(feat + (size_t)s[q] * D)[lane];
        #pragma unroll
        for (int q = 0; q < 8; ++q) {
            acc.x += v[q].x; acc.y += v[q].y; acc.z += v[q].z; acc.w += v[q].w;
        }
    }
    for (; j < cnt; ++j) {
        int s = bk[j];
        float4 v = reinterpret_cast<const float4*>(feat + (size_t)s * D)[lane];
        acc.x += v.x; acc.y += v.y; acc.z += v.z; acc.w += v.w;
    }
    reinterpret_cast<float4*>(out + (size_t)wave * D)[lane] = acc;
}

// Cleanup for (astronomically rare) bucket overflow: one wave per ovf edge.
__global__ __launch_bounds__(256) void k_ovf(const float* __restrict__ feat,
                                             const int* __restrict__ ovf,
                                             const int* __restrict__ ovf_cnt,
                                             float* __restrict__ out) {
    int nw = (gridDim.x * blockDim.x) >> 6;
    int wave = (int)((blockIdx.x * (long)blockDim.x + threadIdx.x) >> 6);
    int lane = threadIdx.x & 63;
    int cnt = *ovf_cnt;
    if (cnt > MAXOVF) cnt = MAXOVF;
    for (int e = wave; e < cnt; e += nw) {
        int s = ovf[2 * e + 0];
        int d = ovf[2 * e + 1];
        float4 v = reinterpret_cast<const float4*>(feat + (size_t)s * D)[lane];
        float* p = out + (size_t)d * D + (size_t)lane * 4;
        atomicAdd(p + 0, v.x);
        atomicAdd(p + 1, v.y);
        atomicAdd(p + 2, v.z);
        atomicAdd(p + 3, v.w);
    }
}

// ================= CSR build (fallback path) =================

__global__ void k_hist(const int* __restrict__ dst, int* __restrict__ counts, int E) {
    for (int e = blockIdx.x * blockDim.x + threadIdx.x; e < E;
         e += gridDim.x * blockDim.x)
        atomicAdd(&counts[dst[e]], 1);
}

__global__ __launch_bounds__(SCAN_THREADS) void k_scan(const int* __restrict__ counts,
                                                       int* __restrict__ offsets,
                                                       int* __restrict__ cursor,
                                                       int N) {
    __shared__ int s[SCAN_THREADS];
    const int t = threadIdx.x;
    const int chunk = (N + SCAN_THREADS - 1) / SCAN_THREADS;
    const int lo = t * chunk;
    const int hi = min(N, lo + chunk);
    int local = 0;
    for (int i = lo; i < hi; ++i) local += counts[i];
    s[t] = local;
    __syncthreads();
    for (int str = 1; str < SCAN_THREADS; str <<= 1) {
        int v = (t >= str) ? s[t - str] : 0;
        __syncthreads();
        s[t] += v;
        __syncthreads();
    }
    int run = s[t] - local;
    for (int i = lo; i < hi; ++i) {
        offsets[i] = run;
        cursor[i] = run;
        run += counts[i];
    }
    if (t == SCAN_THREADS - 1) offsets[N] = s[SCAN_THREADS - 1];
}

__global__ void k_fill(const int* __restrict__ src, const int* __restrict__ dst,
                       int* __restrict__ cursor, int* __restrict__ buckets, int E) {
    for (int e = blockIdx.x * blockDim.x + threadIdx.x; e < E;
         e += gridDim.x * blockDim.x) {
        int pos = atomicAdd(&cursor[dst[e]], 1);
        buckets[pos] = src[e];
    }
}

__global__ __launch_bounds__(256) void k_gather_csr(const float* __restrict__ feat,
                                                    const int* __restrict__ offsets,
                                                    const int* __restrict__ buckets,
                                                    float* __restrict__ out, int N) {
    int wave = (int)((blockIdx.x * (long)blockDim.x + threadIdx.x) >> 6);
    int lane = threadIdx.x & 63;
    if (wave >= N) return;
    const int off = offsets[wave];
    const int end = offsets[wave + 1];
    float4 acc = reinterpret_cast<const float4*>(feat + (size_t)wave * D)[lane];
    int j = off;
    for (; j + 8 <= end; j += 8) {
        int s[8];
        #pragma unroll
        for (int q = 0; q < 8; ++q) s[q] = buckets[j + q];
        float4 v[8];
        #pragma unroll
        for (int q = 0; q < 8; ++q)
            v[q] = reinterpret_cast<const float4*>(feat + (size_t)s[q] * D)[lane];
        #pragma unroll
        for (int q = 0; q < 8; ++q) {
            acc.x += v[q].x; acc.y += v[q].y; acc.z += v[q].z; acc.w += v[q].w;
        }
    }
    for (; j < end; ++j) {
        int s = buckets[j];
        float4 v = reinterpret_cast<const float4*>(feat + (size_t)s * D)[lane];
        acc.x += v.x; acc.y += v.y; acc.z += v.z; acc.w += v.w;
    }
    reinterpret_cast<float4*>(out + (size_t)wave * D)[lane] = acc;
}

// ================= atomic scatter (last-resort fallback) =================

__global__ __launch_bounds__(256) void gc_copy(const float* __restrict__ feat,
                                               float* __restrict__ agg, long n4) {
    long i = (long)blockIdx.x * blockDim.x + threadIdx.x;
    if (i < n4)
        reinterpret_cast<float4*>(agg)[i] = reinterpret_cast<const float4*>(feat)[i];
}

__global__ __launch_bounds__(256) void gc_scatter(const float* __restrict__ feat,
                                                  const int* __restrict__ src,
                                                  const int* __restrict__ dst,
                                                  float* __restrict__ agg, int n_edges) {
    int wave = (int)((blockIdx.x * (long)blockDim.x + threadIdx.x) >> 6);
    int lane = threadIdx.x & 63;
    if (wave >= n_edges) return;
    int s = src[wave];
    int d = dst[wave];
    const float4 v = reinterpret_cast<const float4*>(feat + (size_t)s * D)[lane];
    float* p = agg + (size_t)d * D + (size_t)lane * 4;
    atomicAdd(p + 0, v.x);
    atomicAdd(p + 1, v.y);
    atomicAdd(p + 2, v.z);
    atomicAdd(p + 3, v.w);
}

// ================= GEMM + ReLU, in-place on out =================
// BM=64 rows x 256 cols per block, 256 threads, 8x8 per-thread tile.
// A staged transposed in LDS (2x ds_read_b128 per k); W read from global (L2).
__global__ __launch_bounds__(256) void gemm_relu(const float* __restrict__ Wm,
                                                 float* __restrict__ out, int n_rows) {
    __shared__ float s_aT[GKT][BM + APAD];  // [k][row], ~8.5 KB
    const int t = threadIdx.x;
    const int row0 = blockIdx.x * BM;
    const int rg = t >> 5;          // 0..7
    const int cg = t & 31;          // 0..31
    const int c0 = cg * 8;
    const int r0 = rg * 8;

    float acc[8][8];
    #pragma unroll
    for (int i = 0; i < 8; ++i)
        #pragma unroll
        for (int j = 0; j < 8; ++j) acc[i][j] = 0.f;

    const int srow = t >> 3;  // 0..31
    const int skq = t & 7;    // 0..7 (16B quad within the 128B k-slice)

    for (int kt = 0; kt < D; kt += GKT) {
        // stage A^T: coalesced float4 global reads, transposed b32 LDS writes
        #pragma unroll
        for (int p = 0; p < 2; ++p) {
            int lr = p * 32 + srow;
            int grow = row0 + lr;
            if (grow >= n_rows) grow = n_rows - 1;
            float4 v = *reinterpret_cast<const float4*>(
                &out[(size_t)grow * D + kt + skq * 4]);
            s_aT[skq * 4 + 0][lr] = v.x;
            s_aT[skq * 4 + 1][lr] = v.y;
            s_aT[skq * 4 + 2][lr] = v.z;
            s_aT[skq * 4 + 3][lr] = v.w;
        }
        __syncthreads();

        #pragma unroll 8
        for (int k = 0; k < GKT; ++k) {
            const float4 a0 = *reinterpret_cast<const float4*>(&s_aT[k][r0]);
            const float4 a1 = *reinterpret_cast<const float4*>(&s_aT[k][r0 + 4]);
            const float4 w0 = *reinterpret_cast<const float4*>(
                &Wm[(size_t)(kt + k) * D + c0]);
            const float4 w1 = *reinterpret_cast<const float4*>(
                &Wm[(size_t)(kt + k) * D + c0 + 4]);
            const float av[8] = {a0.x, a0.y, a0.z, a0.w, a1.x, a1.y, a1.z, a1.w};
            const float wv[8] = {w0.x, w0.y, w0.z, w0.w, w1.x, w1.y, w1.z, w1.w};
            #pragma unroll
            for (int i = 0; i < 8; ++i)
                #pragma unroll
                for (int j = 0; j < 8; ++j) acc[i][j] += av[i] * wv[j];
        }
        __syncthreads();
    }

    #pragma unroll
    for (int i = 0; i < 8; ++i) {
        int row = row0 + r0 + i;
        if (row < n_rows) {
            float4 v0, v1;
            v0.x = fmaxf(acc[i][0], 0.f); v0.y = fmaxf(acc[i][1], 0.f);
            v0.z = fmaxf(acc[i][2], 0.f); v0.w = fmaxf(acc[i][3], 0.f);
            v1.x = fmaxf(acc[i][4], 0.f); v1.y = fmaxf(acc[i][5], 0.f);
            v1.z = fmaxf(acc[i][6], 0.f); v1.w = fmaxf(acc[i][7], 0.f);
            *reinterpret_cast<float4*>(&out[(size_t)row * D + c0]) = v0;
            *reinterpret_cast<float4*>(&out[(size_t)row * D + c0 + 4]) = v1;
        }
    }
}

extern "C" void kernel_launch(void* const* d_in, const int* in_sizes, int n_in,
                              void* d_out, int out_size, void* d_ws, size_t ws_size,
                              hipStream_t stream) {
    const float* feat = (const float*)d_in[0];
    const float* W    = (const float*)d_in[1];
    const int*   src  = (const int*)d_in[2];
    const int*   dst  = (const int*)d_in[3];
    float* out = (float*)d_out;

    const int N = in_sizes[0] / D;  // 100000 nodes
    const int E = in_sizes[2];      // 1600000 edges

    // capacity path ws: counts[N] | ovf_cnt[1] | ovf[2*MAXOVF] | buckets[N*CAP]
    const size_t need_cap =
        ((size_t)N + 1 + 2 * MAXOVF + (size_t)N * CAP) * sizeof(int);
    // CSR path ws: counts[N] | offsets[N+1] | cursor[N] | buckets[E]
    const size_t need_csr = ((size_t)3 * N + 1 + (size_t)E) * sizeof(int);

    if (ws_size >= need_cap) {
        int* counts  = (int*)d_ws;
        int* ovf_cnt = counts + N;
        int* ovf     = ovf_cnt + 1;
        int* buckets = ovf + 2 * MAXOVF;

        k_zero<<<(N + 1 + 255) / 256, 256, 0, stream>>>(counts, N + 1);
        k_fillcap<<<2048, 256, 0, stream>>>(src, dst, counts, buckets, ovf, ovf_cnt, E);
        k_gather_cap<<<(N + 3) / 4, 256, 0, stream>>>(feat, counts, buckets, out, N);
        k_ovf<<<8, 256, 0, stream>>>(feat, ovf, ovf_cnt, out);
    } else if (ws_size >= need_csr) {
        int* counts  = (int*)d_ws;
        int* offsets = counts + N;
        int* cursor  = offsets + N + 1;
        int* buckets = cursor + N;

        k_zero<<<(N + 255) / 256, 256, 0, stream>>>(counts, N);
        k_hist<<<2048, 256, 0, stream>>>(dst, counts, E);
        k_scan<<<1, SCAN_THREADS, 0, stream>>>(counts, offsets, cursor, N);
        k_fill<<<2048, 256, 0, stream>>>(src, dst, cursor, buckets, E);
        k_gather_csr<<<(N + 3) / 4, 256, 0, stream>>>(feat, offsets, buckets, out, N);
    } else {
        long n4 = (long)N * D / 4;
        gc_copy<<<(int)((n4 + 255) / 256), 256, 0, stream>>>(feat, out, n4);
        gc_scatter<<<(E + 3) / 4, 256, 0, stream>>>(feat, src, dst, out, E);
    }

    gemm_relu<<<(N + BM - 1) / BM, 256, 0, stream>>>(W, out, N);
}

// Round 5
// 521.201 us; speedup vs baseline: 10.9310x; 1.1835x over previous
//
#include <hip/hip_runtime.h>

#define D 256
#define SCAN_THREADS 1024
#define CAP 48
#define MAXOVF 4096
#define BM 64

typedef float f32x4 __attribute__((ext_vector_type(4)));
typedef short s16x8 __attribute__((ext_vector_type(8)));

__device__ inline unsigned short f2bf(float x) {
    unsigned int u = __float_as_uint(x);
    unsigned int r = (u + 0x7FFFu + ((u >> 16) & 1u)) >> 16;  // RNE
    return (unsigned short)r;
}

// ================= capacity-bucket build (primary path) =================

__global__ void k_zero(int* __restrict__ p, int n) {
    int i = blockIdx.x * blockDim.x + threadIdx.x;
    if (i < n) p[i] = 0;
}

__global__ void k_fillcap(const int* __restrict__ src, const int* __restrict__ dst,
                          int* __restrict__ counts, int* __restrict__ buckets,
                          int* __restrict__ ovf, int* __restrict__ ovf_cnt, int E) {
    for (int e = blockIdx.x * blockDim.x + threadIdx.x; e < E;
         e += gridDim.x * blockDim.x) {
        int d = dst[e];
        int pos = atomicAdd(&counts[d], 1);
        if (pos < CAP) {
            buckets[(size_t)d * CAP + pos] = src[e];
        } else {
            int o = atomicAdd(ovf_cnt, 1);
            if (o < MAXOVF) {
                ovf[2 * o + 0] = src[e];
                ovf[2 * o + 1] = d;
            }
        }
    }
}

__global__ __launch_bounds__(256) void k_gather_cap(const float* __restrict__ feat,
                                                    const int* __restrict__ counts,
                                                    const int* __restrict__ buckets,
                                                    float* __restrict__ out, int N) {
    int wave = (int)((blockIdx.x * (long)blockDim.x + threadIdx.x) >> 6);
    int lane = threadIdx.x & 63;
    if (wave >= N) return;
    int cnt = counts[wave];
    if (cnt > CAP) cnt = CAP;
    const int* bk = buckets + (size_t)wave * CAP;
    float4 acc = reinterpret_cast<const float4*>(feat + (size_t)wave * D)[lane];
    int j = 0;
    for (; j + 8 <= cnt; j += 8) {
        int s[8];
        #pragma unroll
        for (int q = 0; q < 8; ++q) s[q] = bk[j + q];
        float4 v[8];
        #pragma unroll
        for (int q = 0; q < 8; ++q)
            v[q] = reinterpret_cast<const float4*>(feat + (size_t)s[q] * D)[lane];
        #pragma unroll
        for (int q = 0; q < 8; ++q) {
            acc.x += v[q].x; acc.y += v[q].y; acc.z += v[q].z; acc.w += v[q].w;
        }
    }
    for (; j < cnt; ++j) {
        int s = bk[j];
        float4 v = reinterpret_cast<const float4*>(feat + (size_t)s * D)[lane];
        acc.x += v.x; acc.y += v.y; acc.z += v.z; acc.w += v.w;
    }
    reinterpret_cast<float4*>(out + (size_t)wave * D)[lane] = acc;
}

__global__ __launch_bounds__(256) void k_ovf(const float* __restrict__ feat,
                                             const int* __restrict__ ovf,
                                             const int* __restrict__ ovf_cnt,
                                             float* __restrict__ out) {
    int nw = (gridDim.x * blockDim.x) >> 6;
    int wave = (int)((blockIdx.x * (long)blockDim.x + threadIdx.x) >> 6);
    int lane = threadIdx.x & 63;
    int cnt = *ovf_cnt;
    if (cnt > MAXOVF) cnt = MAXOVF;
    for (int e = wave; e < cnt; e += nw) {
        int s = ovf[2 * e + 0];
        int d = ovf[2 * e + 1];
        float4 v = reinterpret_cast<const float4*>(feat + (size_t)s * D)[lane];
        float* p = out + (size_t)d * D + (size_t)lane * 4;
        atomicAdd(p + 0, v.x);
        atomicAdd(p + 1, v.y);
        atomicAdd(p + 2, v.z);
        atomicAdd(p + 3, v.w);
    }
}

// ================= CSR build (fallback path) =================

__global__ void k_hist(const int* __restrict__ dst, int* __restrict__ counts, int E) {
    for (int e = blockIdx.x * blockDim.x + threadIdx.x; e < E;
         e += gridDim.x * blockDim.x)
        atomicAdd(&counts[dst[e]], 1);
}

__global__ __launch_bounds__(SCAN_THREADS) void k_scan(const int* __restrict__ counts,
                                                       int* __restrict__ offsets,
                                                       int* __restrict__ cursor,
                                                       int N) {
    __shared__ int s[SCAN_THREADS];
    const int t = threadIdx.x;
    const int chunk = (N + SCAN_THREADS - 1) / SCAN_THREADS;
    const int lo = t * chunk;
    const int hi = min(N, lo + chunk);
    int local = 0;
    for (int i = lo; i < hi; ++i) local += counts[i];
    s[t] = local;
    __syncthreads();
    for (int str = 1; str < SCAN_THREADS; str <<= 1) {
        int v = (t >= str) ? s[t - str] : 0;
        __syncthreads();
        s[t] += v;
        __syncthreads();
    }
    int run = s[t] - local;
    for (int i = lo; i < hi; ++i) {
        offsets[i] = run;
        cursor[i] = run;
        run += counts[i];
    }
    if (t == SCAN_THREADS - 1) offsets[N] = s[SCAN_THREADS - 1];
}

__global__ void k_fill(const int* __restrict__ src, const int* __restrict__ dst,
                       int* __restrict__ cursor, int* __restrict__ buckets, int E) {
    for (int e = blockIdx.x * blockDim.x + threadIdx.x; e < E;
         e += gridDim.x * blockDim.x) {
        int pos = atomicAdd(&cursor[dst[e]], 1);
        buckets[pos] = src[e];
    }
}

__global__ __launch_bounds__(256) void k_gather_csr(const float* __restrict__ feat,
                                                    const int* __restrict__ offsets,
                                                    const int* __restrict__ buckets,
                                                    float* __restrict__ out, int N) {
    int wave = (int)((blockIdx.x * (long)blockDim.x + threadIdx.x) >> 6);
    int lane = threadIdx.x & 63;
    if (wave >= N) return;
    const int off = offsets[wave];
    const int end = offsets[wave + 1];
    float4 acc = reinterpret_cast<const float4*>(feat + (size_t)wave * D)[lane];
    int j = off;
    for (; j + 8 <= end; j += 8) {
        int s[8];
        #pragma unroll
        for (int q = 0; q < 8; ++q) s[q] = buckets[j + q];
        float4 v[8];
        #pragma unroll
        for (int q = 0; q < 8; ++q)
            v[q] = reinterpret_cast<const float4*>(feat + (size_t)s[q] * D)[lane];
        #pragma unroll
        for (int q = 0; q < 8; ++q) {
            acc.x += v[q].x; acc.y += v[q].y; acc.z += v[q].z; acc.w += v[q].w;
        }
    }
    for (; j < end; ++j) {
        int s = buckets[j];
        float4 v = reinterpret_cast<const float4*>(feat + (size_t)s * D)[lane];
        acc.x += v.x; acc.y += v.y; acc.z += v.z; acc.w += v.w;
    }
    reinterpret_cast<float4*>(out + (size_t)wave * D)[lane] = acc;
}

// ================= atomic scatter (last-resort fallback) =================

__global__ __launch_bounds__(256) void gc_copy(const float* __restrict__ feat,
                                               float* __restrict__ agg, long n4) {
    long i = (long)blockIdx.x * blockDim.x + threadIdx.x;
    if (i < n4)
        reinterpret_cast<float4*>(agg)[i] = reinterpret_cast<const float4*>(feat)[i];
}

__global__ __launch_bounds__(256) void gc_scatter(const float* __restrict__ feat,
                                                  const int* __restrict__ src,
                                                  const int* __restrict__ dst,
                                                  float* __restrict__ agg, int n_edges) {
    int wave = (int)((blockIdx.x * (long)blockDim.x + threadIdx.x) >> 6);
    int lane = threadIdx.x & 63;
    if (wave >= n_edges) return;
    int s = src[wave];
    int d = dst[wave];
    const float4 v = reinterpret_cast<const float4*>(feat + (size_t)s * D)[lane];
    float* p = agg + (size_t)d * D + (size_t)lane * 4;
    atomicAdd(p + 0, v.x);
    atomicAdd(p + 1, v.y);
    atomicAdd(p + 2, v.z);
    atomicAdd(p + 3, v.w);
}

// ================= W -> W^T bf16 conversion =================
// wT[col][k], bf16 bits. Coalesced writes; strided reads (W is 256KB, L2).
__global__ __launch_bounds__(256) void k_wT(const float* __restrict__ W,
                                            unsigned short* __restrict__ wT) {
    int col = blockIdx.x;   // 0..255
    int k = threadIdx.x;    // 0..255
    wT[(size_t)col * D + k] = f2bf(W[(size_t)k * D + col]);
}

// ================= MFMA GEMM + ReLU, in-place on out =================
// 64 rows/block, 256 cols, K=256. 4 waves; wave w owns rows w*16..+15.
// A: fp32 from out -> bf16 -> XOR-swizzled LDS; B: bf16 frags from wT (L2).
__global__ __launch_bounds__(256) void gemm_mfma(const unsigned short* __restrict__ wT,
                                                 float* __restrict__ out, int n_rows) {
    __shared__ __align__(16) unsigned char s_a[BM * 512];  // 64 rows x 256 bf16
    const int t = threadIdx.x;
    const int row0 = blockIdx.x * BM;
    const int wv = t >> 6;
    const int l = t & 63;

    // ---- stage A: coalesced float4 reads, convert, swizzled 8B LDS writes
    #pragma unroll
    for (int i = 0; i < 16; ++i) {
        int f4 = t + 256 * i;        // 0..4095 float4s of the 64x256 tile
        int row = f4 >> 6;           // 0..63
        int kc = f4 & 63;            // float4 index within row
        int grow = row0 + row;
        if (grow >= n_rows) grow = n_rows - 1;
        float4 v = *reinterpret_cast<const float4*>(out + (size_t)grow * D + kc * 4);
        uint2 u;
        u.x = (unsigned)f2bf(v.x) | ((unsigned)f2bf(v.y) << 16);
        u.y = (unsigned)f2bf(v.z) | ((unsigned)f2bf(v.w) << 16);
        int byte = (row * 512 + kc * 8) ^ ((row & 7) << 4);
        *reinterpret_cast<uint2*>(s_a + byte) = u;
    }
    __syncthreads();

    f32x4 acc[16];
    #pragma unroll
    for (int ct = 0; ct < 16; ++ct) acc[ct] = (f32x4){0.f, 0.f, 0.f, 0.f};

    const int lr = wv * 16 + (l & 15);       // A row (LDS index)
    #pragma unroll
    for (int ks = 0; ks < 8; ++ks) {
        const int kb = ks * 32 + (l >> 4) * 8;  // k base for this lane
        const int ab = (lr * 512 + kb * 2) ^ ((lr & 7) << 4);
        s16x8 af = *reinterpret_cast<const s16x8*>(s_a + ab);
        #pragma unroll
        for (int ct = 0; ct < 16; ++ct) {
            s16x8 bf = *reinterpret_cast<const s16x8*>(
                wT + (size_t)(ct * 16 + (l & 15)) * D + kb);
            acc[ct] = __builtin_amdgcn_mfma_f32_16x16x32_bf16(af, bf, acc[ct], 0, 0, 0);
        }
    }

    // ---- epilogue: C/D map col=lane&15, row=(lane>>4)*4+reg (m89)
    const int rbase = row0 + wv * 16 + (l >> 4) * 4;
    const int cb = l & 15;
    #pragma unroll
    for (int ct = 0; ct < 16; ++ct) {
        #pragma unroll
        for (int r = 0; r < 4; ++r) {
            int row = rbase + r;
            if (row < n_rows)
                out[(size_t)row * D + ct * 16 + cb] = fmaxf(acc[ct][r], 0.f);
        }
    }
}

// legacy fp32 GEMM (only for the no-workspace fallback)
__global__ __launch_bounds__(256) void gemm_relu(const float* __restrict__ Wm,
                                                 float* __restrict__ out, int n_rows) {
    __shared__ float s_a[32][D];
    const int row0 = blockIdx.x * 32;
    const int c = threadIdx.x;
    {
        const float4* gsrc = reinterpret_cast<const float4*>(out + (size_t)row0 * D);
        float4* ldst = reinterpret_cast<float4*>(&s_a[0][0]);
        #pragma unroll
        for (int i = 0; i < 8; ++i)
            ldst[threadIdx.x + i * 256] = gsrc[threadIdx.x + i * 256];
    }
    __syncthreads();
    float acc[32];
    #pragma unroll
    for (int r = 0; r < 32; ++r) acc[r] = 0.f;
    #pragma unroll 4
    for (int k = 0; k < D; ++k) {
        float w = Wm[(size_t)k * D + c];
        #pragma unroll
        for (int r = 0; r < 32; ++r) acc[r] += s_a[r][k] * w;
    }
    #pragma unroll
    for (int r = 0; r < 32; ++r) {
        int row = row0 + r;
        if (row < n_rows) out[(size_t)row * D + c] = fmaxf(acc[r], 0.f);
    }
}

extern "C" void kernel_launch(void* const* d_in, const int* in_sizes, int n_in,
                              void* d_out, int out_size, void* d_ws, size_t ws_size,
                              hipStream_t stream) {
    const float* feat = (const float*)d_in[0];
    const float* W    = (const float*)d_in[1];
    const int*   src  = (const int*)d_in[2];
    const int*   dst  = (const int*)d_in[3];
    float* out = (float*)d_out;

    const int N = in_sizes[0] / D;  // 100000 nodes
    const int E = in_sizes[2];      // 1600000 edges
    const size_t WT_BYTES = (size_t)D * D * 2;  // 128KB bf16 W^T

    const size_t need_cap =
        ((size_t)N + 1 + 2 * MAXOVF + (size_t)N * CAP) * sizeof(int);
    const size_t need_csr = ((size_t)3 * N + 1 + (size_t)E) * sizeof(int);
    const int gemm_blocks = (N + BM - 1) / BM;

    if (ws_size >= need_cap) {
        int* counts  = (int*)d_ws;
        int* ovf_cnt = counts + N;
        int* ovf     = ovf_cnt + 1;
        int* buckets = ovf + 2 * MAXOVF;

        const bool wt_early = ws_size >= need_cap + WT_BYTES + 256;
        unsigned short* wT;
        if (wt_early) {
            wT = (unsigned short*)(((uintptr_t)d_ws + need_cap + 255) & ~(uintptr_t)255);
            k_wT<<<D, 256, 0, stream>>>(W, wT);  // independent; hides under build
        } else {
            // reuse buckets region after the gather has consumed it
            wT = (unsigned short*)(((uintptr_t)buckets + 255) & ~(uintptr_t)255);
        }

        k_zero<<<(N + 1 + 255) / 256, 256, 0, stream>>>(counts, N + 1);
        k_fillcap<<<2048, 256, 0, stream>>>(src, dst, counts, buckets, ovf, ovf_cnt, E);
        k_gather_cap<<<(N + 3) / 4, 256, 0, stream>>>(feat, counts, buckets, out, N);
        k_ovf<<<8, 256, 0, stream>>>(feat, ovf, ovf_cnt, out);
        if (!wt_early) k_wT<<<D, 256, 0, stream>>>(W, wT);
        gemm_mfma<<<gemm_blocks, 256, 0, stream>>>(wT, out, N);
    } else if (ws_size >= need_csr) {
        int* counts  = (int*)d_ws;
        int* offsets = counts + N;
        int* cursor  = offsets + N + 1;
        int* buckets = cursor + N;

        k_zero<<<(N + 255) / 256, 256, 0, stream>>>(counts, N);
        k_hist<<<2048, 256, 0, stream>>>(dst, counts, E);
        k_scan<<<1, SCAN_THREADS, 0, stream>>>(counts, offsets, cursor, N);
        k_fill<<<2048, 256, 0, stream>>>(src, dst, cursor, buckets, E);
        k_gather_csr<<<(N + 3) / 4, 256, 0, stream>>>(feat, offsets, buckets, out, N);
        unsigned short* wT =
            (unsigned short*)(((uintptr_t)buckets + 255) & ~(uintptr_t)255);
        k_wT<<<D, 256, 0, stream>>>(W, wT);
        gemm_mfma<<<gemm_blocks, 256, 0, stream>>>(wT, out, N);
    } else {
        long n4 = (long)N * D / 4;
        gc_copy<<<(int)((n4 + 255) / 256), 256, 0, stream>>>(feat, out, n4);
        gc_scatter<<<(E + 3) / 4, 256, 0, stream>>>(feat, src, dst, out, E);
        gemm_relu<<<(N + 31) / 32, 256, 0, stream>>>(W, out, N);
    }
}

// Round 6
// 401.021 us; speedup vs baseline: 14.2068x; 1.2997x over previous
//
#include <hip/hip_runtime.h>

#define D 256
#define SCAN_THREADS 1024
#define CAP 32
#define MAXOVF 4096
#define BM 64

typedef float f32x4 __attribute__((ext_vector_type(4)));
typedef short s16x8 __attribute__((ext_vector_type(8)));

__device__ inline unsigned int f2bf(float x) {
    unsigned int u = __float_as_uint(x);
    return (u + 0x7FFFu + ((u >> 16) & 1u)) >> 16;  // RNE, low 16 bits valid
}
__device__ inline float bflo(unsigned int u) { return __uint_as_float(u << 16); }
__device__ inline float bfhi(unsigned int u) { return __uint_as_float(u & 0xFFFF0000u); }

// ================= small utility kernels =================

__global__ void k_zero(int* __restrict__ p, int n) {
    int i = blockIdx.x * blockDim.x + threadIdx.x;
    if (i < n) p[i] = 0;
}

// feat fp32 -> bf16 (packed), 8 elems/thread
__global__ __launch_bounds__(256) void k_f2b(const float* __restrict__ f,
                                             unsigned short* __restrict__ fb, long n8) {
    for (long i = blockIdx.x * 256L + threadIdx.x; i < n8; i += (long)gridDim.x * 256) {
        const float4* p = reinterpret_cast<const float4*>(f + i * 8);
        float4 a = p[0], b = p[1];
        uint4 u;
        u.x = f2bf(a.x) | (f2bf(a.y) << 16);
        u.y = f2bf(a.z) | (f2bf(a.w) << 16);
        u.z = f2bf(b.x) | (f2bf(b.y) << 16);
        u.w = f2bf(b.z) | (f2bf(b.w) << 16);
        reinterpret_cast<uint4*>(fb)[i] = u;
    }
}

// W[k][col] fp32 -> wT[col][k] bf16
__global__ __launch_bounds__(256) void k_wT(const float* __restrict__ W,
                                            unsigned short* __restrict__ wT) {
    int col = blockIdx.x;
    int k = threadIdx.x;
    wT[(size_t)col * D + k] = (unsigned short)f2bf(W[(size_t)k * D + col]);
}

// ================= capacity-bucket build =================

__global__ void k_fillcap(const int* __restrict__ src, const int* __restrict__ dst,
                          int* __restrict__ counts, int* __restrict__ buckets,
                          int* __restrict__ ovf, int* __restrict__ ovf_cnt, int E) {
    for (int e = blockIdx.x * blockDim.x + threadIdx.x; e < E;
         e += gridDim.x * blockDim.x) {
        int d = dst[e];
        int pos = atomicAdd(&counts[d], 1);
        if (pos < CAP) {
            buckets[(size_t)d * CAP + pos] = src[e];
        } else {
            int o = atomicAdd(ovf_cnt, 1);
            if (o < MAXOVF) {
                ovf[2 * o + 0] = src[e];
                ovf[2 * o + 1] = d;
            }
        }
    }
}

// ================= gathers (one wave per node) =================
// Tier A: bf16 feat reads, fp32 accum, swizzled bf16 agg write to ws.
__global__ __launch_bounds__(256) void g_bf_aggb(const unsigned short* __restrict__ fb,
                                                 const int* __restrict__ counts,
                                                 const int* __restrict__ buckets,
                                                 const int* __restrict__ ovf,
                                                 const int* __restrict__ ovf_cnt,
                                                 unsigned short* __restrict__ aggb, int N) {
    int node = (int)((blockIdx.x * (long)blockDim.x + threadIdx.x) >> 6);
    int ln = threadIdx.x & 63;
    if (node >= N) return;
    int cnt_raw = counts[node];
    int cnt = cnt_raw > CAP ? CAP : cnt_raw;
    const int* bk = buckets + (size_t)node * CAP;
    uint2 u = reinterpret_cast<const uint2*>(fb + (size_t)node * D)[ln];
    float4 acc;
    acc.x = bflo(u.x); acc.y = bfhi(u.x); acc.z = bflo(u.y); acc.w = bfhi(u.y);
    int j = 0;
    for (; j + 8 <= cnt; j += 8) {
        int s[8];
        #pragma unroll
        for (int q = 0; q < 8; ++q) s[q] = bk[j + q];
        uint2 v[8];
        #pragma unroll
        for (int q = 0; q < 8; ++q)
            v[q] = reinterpret_cast<const uint2*>(fb + (size_t)s[q] * D)[ln];
        #pragma unroll
        for (int q = 0; q < 8; ++q) {
            acc.x += bflo(v[q].x); acc.y += bfhi(v[q].x);
            acc.z += bflo(v[q].y); acc.w += bfhi(v[q].y);
        }
    }
    for (; j < cnt; ++j) {
        uint2 v = reinterpret_cast<const uint2*>(fb + (size_t)bk[j] * D)[ln];
        acc.x += bflo(v.x); acc.y += bfhi(v.x);
        acc.z += bflo(v.y); acc.w += bfhi(v.y);
    }
    if (cnt_raw > CAP) {  // astronomically rare; exact cleanup
        int m = *ovf_cnt;
        if (m > MAXOVF) m = MAXOVF;
        for (int e = 0; e < m; ++e) {
            if (ovf[2 * e + 1] == node) {
                uint2 v = reinterpret_cast<const uint2*>(fb + (size_t)ovf[2 * e] * D)[ln];
                acc.x += bflo(v.x); acc.y += bfhi(v.x);
                acc.z += bflo(v.y); acc.w += bfhi(v.y);
            }
        }
    }
    uint2 w;
    w.x = f2bf(acc.x) | (f2bf(acc.y) << 16);
    w.y = f2bf(acc.z) | (f2bf(acc.w) << 16);
    // XOR-swizzled within-row placement (byte = (ln*8) ^ ((node&7)<<4))
    unsigned short* rowp = aggb + (size_t)node * D;
    int us = (ln * 4) ^ ((node & 7) << 3);
    *reinterpret_cast<uint2*>(rowp + us) = w;
}

// Tier B: bf16 feat reads, fp32 agg write to d_out.
__global__ __launch_bounds__(256) void g_bf_out(const unsigned short* __restrict__ fb,
                                                const int* __restrict__ counts,
                                                const int* __restrict__ buckets,
                                                const int* __restrict__ ovf,
                                                const int* __restrict__ ovf_cnt,
                                                float* __restrict__ out, int N) {
    int node = (int)((blockIdx.x * (long)blockDim.x + threadIdx.x) >> 6);
    int ln = threadIdx.x & 63;
    if (node >= N) return;
    int cnt_raw = counts[node];
    int cnt = cnt_raw > CAP ? CAP : cnt_raw;
    const int* bk = buckets + (size_t)node * CAP;
    uint2 u = reinterpret_cast<const uint2*>(fb + (size_t)node * D)[ln];
    float4 acc;
    acc.x = bflo(u.x); acc.y = bfhi(u.x); acc.z = bflo(u.y); acc.w = bfhi(u.y);
    int j = 0;
    for (; j + 8 <= cnt; j += 8) {
        int s[8];
        #pragma unroll
        for (int q = 0; q < 8; ++q) s[q] = bk[j + q];
        uint2 v[8];
        #pragma unroll
        for (int q = 0; q < 8; ++q)
            v[q] = reinterpret_cast<const uint2*>(fb + (size_t)s[q] * D)[ln];
        #pragma unroll
        for (int q = 0; q < 8; ++q) {
            acc.x += bflo(v[q].x); acc.y += bfhi(v[q].x);
            acc.z += bflo(v[q].y); acc.w += bfhi(v[q].y);
        }
    }
    for (; j < cnt; ++j) {
        uint2 v = reinterpret_cast<const uint2*>(fb + (size_t)bk[j] * D)[ln];
        acc.x += bflo(v.x); acc.y += bfhi(v.x);
        acc.z += bflo(v.y); acc.w += bfhi(v.y);
    }
    if (cnt_raw > CAP) {
        int m = *ovf_cnt;
        if (m > MAXOVF) m = MAXOVF;
        for (int e = 0; e < m; ++e) {
            if (ovf[2 * e + 1] == node) {
                uint2 v = reinterpret_cast<const uint2*>(fb + (size_t)ovf[2 * e] * D)[ln];
                acc.x += bflo(v.x); acc.y += bfhi(v.x);
                acc.z += bflo(v.y); acc.w += bfhi(v.y);
            }
        }
    }
    reinterpret_cast<float4*>(out + (size_t)node * D)[ln] = acc;
}

// Tier C: fp32 feat reads, fp32 agg write to d_out (round-5 behavior + ovf scan).
__global__ __launch_bounds__(256) void g_f32_out(const float* __restrict__ feat,
                                                 const int* __restrict__ counts,
                                                 const int* __restrict__ buckets,
                                                 const int* __restrict__ ovf,
                                                 const int* __restrict__ ovf_cnt,
                                                 float* __restrict__ out, int N) {
    int node = (int)((blockIdx.x * (long)blockDim.x + threadIdx.x) >> 6);
    int ln = threadIdx.x & 63;
    if (node >= N) return;
    int cnt_raw = counts[node];
    int cnt = cnt_raw > CAP ? CAP : cnt_raw;
    const int* bk = buckets + (size_t)node * CAP;
    float4 acc = reinterpret_cast<const float4*>(feat + (size_t)node * D)[ln];
    int j = 0;
    for (; j + 8 <= cnt; j += 8) {
        int s[8];
        #pragma unroll
        for (int q = 0; q < 8; ++q) s[q] = bk[j + q];
        float4 v[8];
        #pragma unroll
        for (int q = 0; q < 8; ++q)
            v[q] = reinterpret_cast<const float4*>(feat + (size_t)s[q] * D)[ln];
        #pragma unroll
        for (int q = 0; q < 8; ++q) {
            acc.x += v[q].x; acc.y += v[q].y; acc.z += v[q].z; acc.w += v[q].w;
        }
    }
    for (; j < cnt; ++j) {
        float4 v = reinterpret_cast<const float4*>(feat + (size_t)bk[j] * D)[ln];
        acc.x += v.x; acc.y += v.y; acc.z += v.z; acc.w += v.w;
    }
    if (cnt_raw > CAP) {
        int m = *ovf_cnt;
        if (m > MAXOVF) m = MAXOVF;
        for (int e = 0; e < m; ++e) {
            if (ovf[2 * e + 1] == node) {
                float4 v = reinterpret_cast<const float4*>(feat + (size_t)ovf[2 * e] * D)[ln];
                acc.x += v.x; acc.y += v.y; acc.z += v.z; acc.w += v.w;
            }
        }
    }
    reinterpret_cast<float4*>(out + (size_t)node * D)[ln] = acc;
}

// ================= CSR build (fallback path) =================

__global__ void k_hist(const int* __restrict__ dst, int* __restrict__ counts, int E) {
    for (int e = blockIdx.x * blockDim.x + threadIdx.x; e < E;
         e += gridDim.x * blockDim.x)
        atomicAdd(&counts[dst[e]], 1);
}

__global__ __launch_bounds__(SCAN_THREADS) void k_scan(const int* __restrict__ counts,
                                                       int* __restrict__ offsets,
                                                       int* __restrict__ cursor,
                                                       int N) {
    __shared__ int s[SCAN_THREADS];
    const int t = threadIdx.x;
    const int chunk = (N + SCAN_THREADS - 1) / SCAN_THREADS;
    const int lo = t * chunk;
    const int hi = min(N, lo + chunk);
    int local = 0;
    for (int i = lo; i < hi; ++i) local += counts[i];
    s[t] = local;
    __syncthreads();
    for (int str = 1; str < SCAN_THREADS; str <<= 1) {
        int v = (t >= str) ? s[t - str] : 0;
        __syncthreads();
        s[t] += v;
        __syncthreads();
    }
    int run = s[t] - local;
    for (int i = lo; i < hi; ++i) {
        offsets[i] = run;
        cursor[i] = run;
        run += counts[i];
    }
    if (t == SCAN_THREADS - 1) offsets[N] = s[SCAN_THREADS - 1];
}

__global__ void k_fill(const int* __restrict__ src, const int* __restrict__ dst,
                       int* __restrict__ cursor, int* __restrict__ buckets, int E) {
    for (int e = blockIdx.x * blockDim.x + threadIdx.x; e < E;
         e += gridDim.x * blockDim.x) {
        int pos = atomicAdd(&cursor[dst[e]], 1);
        buckets[pos] = src[e];
    }
}

__global__ __launch_bounds__(256) void k_gather_csr(const float* __restrict__ feat,
                                                    const int* __restrict__ offsets,
                                                    const int* __restrict__ buckets,
                                                    float* __restrict__ out, int N) {
    int wave = (int)((blockIdx.x * (long)blockDim.x + threadIdx.x) >> 6);
    int lane = threadIdx.x & 63;
    if (wave >= N) return;
    const int off = offsets[wave];
    const int end = offsets[wave + 1];
    float4 acc = reinterpret_cast<const float4*>(feat + (size_t)wave * D)[lane];
    int j = off;
    for (; j + 8 <= end; j += 8) {
        int s[8];
        #pragma unroll
        for (int q = 0; q < 8; ++q) s[q] = buckets[j + q];
        float4 v[8];
        #pragma unroll
        for (int q = 0; q < 8; ++q)
            v[q] = reinterpret_cast<const float4*>(feat + (size_t)s[q] * D)[lane];
        #pragma unroll
        for (int q = 0; q < 8; ++q) {
            acc.x += v[q].x; acc.y += v[q].y; acc.z += v[q].z; acc.w += v[q].w;
        }
    }
    for (; j < end; ++j) {
        float4 v = reinterpret_cast<const float4*>(feat + (size_t)buckets[j] * D)[lane];
        acc.x += v.x; acc.y += v.y; acc.z += v.z; acc.w += v.w;
    }
    reinterpret_cast<float4*>(out + (size_t)wave * D)[lane] = acc;
}

// ================= atomic scatter (last-resort) =================

__global__ __launch_bounds__(256) void gc_copy(const float* __restrict__ feat,
                                               float* __restrict__ agg, long n4) {
    long i = (long)blockIdx.x * blockDim.x + threadIdx.x;
    if (i < n4)
        reinterpret_cast<float4*>(agg)[i] = reinterpret_cast<const float4*>(feat)[i];
}

__global__ __launch_bounds__(256) void gc_scatter(const float* __restrict__ feat,
                                                  const int* __restrict__ src,
                                                  const int* __restrict__ dst,
                                                  float* __restrict__ agg, int n_edges) {
    int wave = (int)((blockIdx.x * (long)blockDim.x + threadIdx.x) >> 6);
    int lane = threadIdx.x & 63;
    if (wave >= n_edges) return;
    int s = src[wave];
    int d = dst[wave];
    const float4 v = reinterpret_cast<const float4*>(feat + (size_t)s * D)[lane];
    float* p = agg + (size_t)d * D + (size_t)lane * 4;
    atomicAdd(p + 0, v.x);
    atomicAdd(p + 1, v.y);
    atomicAdd(p + 2, v.z);
    atomicAdd(p + 3, v.w);
}

// ================= MFMA GEMMs =================
// Shared MFMA core: A-frags from swizzled LDS image, B from wT (L2).
// Tier A: A staged via global_load_lds from swizzled bf16 agg in ws.
__global__ __launch_bounds__(256) void gemm_mfma_b(const unsigned short* __restrict__ aggb,
                                                   const unsigned short* __restrict__ wT,
                                                   float* __restrict__ out, int n_rows) {
    __shared__ __align__(16) unsigned char s_a[BM * 512];  // 64 rows x 256 bf16
    const int t = threadIdx.x;
    const int row0 = blockIdx.x * BM;
    const int wv = t >> 6;
    const int l = t & 63;

    const char* gbase = reinterpret_cast<const char*>(aggb) + (size_t)row0 * 512;
    #pragma unroll
    for (int q = 0; q < 8; ++q) {
        int off = wv * 8192 + q * 1024;
        __builtin_amdgcn_global_load_lds(
            (const __attribute__((address_space(1))) void*)(gbase + off + l * 16),
            (__attribute__((address_space(3))) void*)(s_a + off), 16, 0, 0);
    }
    __syncthreads();

    f32x4 acc[16];
    #pragma unroll
    for (int ct = 0; ct < 16; ++ct) acc[ct] = (f32x4){0.f, 0.f, 0.f, 0.f};

    const int lr = wv * 16 + (l & 15);
    #pragma unroll
    for (int ks = 0; ks < 8; ++ks) {
        const int kb = ks * 32 + (l >> 4) * 8;
        const int ab = (lr * 512 + kb * 2) ^ ((lr & 7) << 4);
        s16x8 af = *reinterpret_cast<const s16x8*>(s_a + ab);
        #pragma unroll
        for (int ct = 0; ct < 16; ++ct) {
            s16x8 bf = *reinterpret_cast<const s16x8*>(
                wT + (size_t)(ct * 16 + (l & 15)) * D + kb);
            acc[ct] = __builtin_amdgcn_mfma_f32_16x16x32_bf16(af, bf, acc[ct], 0, 0, 0);
        }
    }

    const int rbase = row0 + wv * 16 + (l >> 4) * 4;
    const int cb = l & 15;
    #pragma unroll
    for (int ct = 0; ct < 16; ++ct) {
        #pragma unroll
        for (int r = 0; r < 4; ++r) {
            int row = rbase + r;
            if (row < n_rows)
                out[(size_t)row * D + ct * 16 + cb] = fmaxf(acc[ct][r], 0.f);
        }
    }
}

// Tiers B/C: A read fp32 from out (in-place), converted + swizzled reg->LDS.
__global__ __launch_bounds__(256) void gemm_mfma(const unsigned short* __restrict__ wT,
                                                 float* __restrict__ out, int n_rows) {
    __shared__ __align__(16) unsigned char s_a[BM * 512];
    const int t = threadIdx.x;
    const int row0 = blockIdx.x * BM;
    const int wv = t >> 6;
    const int l = t & 63;

    #pragma unroll
    for (int i = 0; i < 16; ++i) {
        int f4 = t + 256 * i;
        int row = f4 >> 6;
        int kc = f4 & 63;
        int grow = row0 + row;
        if (grow >= n_rows) grow = n_rows - 1;
        float4 v = *reinterpret_cast<const float4*>(out + (size_t)grow * D + kc * 4);
        uint2 u;
        u.x = f2bf(v.x) | (f2bf(v.y) << 16);
        u.y = f2bf(v.z) | (f2bf(v.w) << 16);
        int byte = (row * 512 + kc * 8) ^ ((row & 7) << 4);
        *reinterpret_cast<uint2*>(s_a + byte) = u;
    }
    __syncthreads();

    f32x4 acc[16];
    #pragma unroll
    for (int ct = 0; ct < 16; ++ct) acc[ct] = (f32x4){0.f, 0.f, 0.f, 0.f};

    const int lr = wv * 16 + (l & 15);
    #pragma unroll
    for (int ks = 0; ks < 8; ++ks) {
        const int kb = ks * 32 + (l >> 4) * 8;
        const int ab = (lr * 512 + kb * 2) ^ ((lr & 7) << 4);
        s16x8 af = *reinterpret_cast<const s16x8*>(s_a + ab);
        #pragma unroll
        for (int ct = 0; ct < 16; ++ct) {
            s16x8 bf = *reinterpret_cast<const s16x8*>(
                wT + (size_t)(ct * 16 + (l & 15)) * D + kb);
            acc[ct] = __builtin_amdgcn_mfma_f32_16x16x32_bf16(af, bf, acc[ct], 0, 0, 0);
        }
    }

    const int rbase = row0 + wv * 16 + (l >> 4) * 4;
    const int cb = l & 15;
    #pragma unroll
    for (int ct = 0; ct < 16; ++ct) {
        #pragma unroll
        for (int r = 0; r < 4; ++r) {
            int row = rbase + r;
            if (row < n_rows)
                out[(size_t)row * D + ct * 16 + cb] = fmaxf(acc[ct][r], 0.f);
        }
    }
}

// legacy fp32 GEMM (no-workspace fallback)
__global__ __launch_bounds__(256) void gemm_relu(const float* __restrict__ Wm,
                                                 float* __restrict__ out, int n_rows) {
    __shared__ float s_a[32][D];
    const int row0 = blockIdx.x * 32;
    const int c = threadIdx.x;
    {
        const float4* gsrc = reinterpret_cast<const float4*>(out + (size_t)row0 * D);
        float4* ldst = reinterpret_cast<float4*>(&s_a[0][0]);
        #pragma unroll
        for (int i = 0; i < 8; ++i)
            ldst[threadIdx.x + i * 256] = gsrc[threadIdx.x + i * 256];
    }
    __syncthreads();
    float acc[32];
    #pragma unroll
    for (int r = 0; r < 32; ++r) acc[r] = 0.f;
    #pragma unroll 4
    for (int k = 0; k < D; ++k) {
        float w = Wm[(size_t)k * D + c];
        #pragma unroll
        for (int r = 0; r < 32; ++r) acc[r] += s_a[r][k] * w;
    }
    #pragma unroll
    for (int r = 0; r < 32; ++r) {
        int row = row0 + r;
        if (row < n_rows) out[(size_t)row * D + c] = fmaxf(acc[r], 0.f);
    }
}

extern "C" void kernel_launch(void* const* d_in, const int* in_sizes, int n_in,
                              void* d_out, int out_size, void* d_ws, size_t ws_size,
                              hipStream_t stream) {
    const float* feat = (const float*)d_in[0];
    const float* W    = (const float*)d_in[1];
    const int*   src  = (const int*)d_in[2];
    const int*   dst  = (const int*)d_in[3];
    float* out = (float*)d_out;

    const int N = in_sizes[0] / D;  // 100000
    const int E = in_sizes[2];      // 1600000
    const int Npad = ((N + BM - 1) / BM) * BM;
    auto al = [](size_t x) { return (x + 255) & ~(size_t)255; };

    // cap structures: counts[N] | ovf_cnt[1] | ovf[2*MAXOVF] | buckets[N*CAP]
    const size_t cap_bytes = ((size_t)N + 1 + 2 * MAXOVF + (size_t)N * CAP) * 4;
    const size_t featb_off = al(cap_bytes);
    const size_t featb_sz  = (size_t)N * D * 2;
    const size_t wt_off    = al(featb_off + featb_sz);
    const size_t wt_sz     = (size_t)D * D * 2;
    const size_t aggb_off  = al(wt_off + wt_sz);
    const size_t aggb_sz   = (size_t)Npad * D * 2;

    const size_t need_A   = aggb_off + aggb_sz;   // ~116 MB
    const size_t need_B   = wt_off + wt_sz;       // ~65 MB
    const size_t need_C   = cap_bytes;            // ~13.3 MB (wT aliases buckets)
    const size_t need_csr = ((size_t)3 * N + 1 + (size_t)E) * 4;

    const int gemm_blocks = (N + BM - 1) / BM;
    const int gat_blocks = (N + 3) / 4;

    if (ws_size >= need_C) {
        char* base = (char*)d_ws;
        int* counts  = (int*)base;
        int* ovf_cnt = counts + N;
        int* ovf     = ovf_cnt + 1;
        int* buckets = ovf + 2 * MAXOVF;

        k_zero<<<(N + 1 + 255) / 256, 256, 0, stream>>>(counts, N + 1);

        if (ws_size >= need_A) {
            unsigned short* featb = (unsigned short*)(base + featb_off);
            unsigned short* wT    = (unsigned short*)(base + wt_off);
            unsigned short* aggb  = (unsigned short*)(base + aggb_off);
            k_f2b<<<2048, 256, 0, stream>>>(feat, featb, (long)N * D / 8);
            k_wT<<<D, 256, 0, stream>>>(W, wT);
            k_fillcap<<<2048, 256, 0, stream>>>(src, dst, counts, buckets, ovf, ovf_cnt, E);
            g_bf_aggb<<<gat_blocks, 256, 0, stream>>>(featb, counts, buckets, ovf, ovf_cnt, aggb, N);
            gemm_mfma_b<<<gemm_blocks, 256, 0, stream>>>(aggb, wT, out, N);
        } else if (ws_size >= need_B) {
            unsigned short* featb = (unsigned short*)(base + featb_off);
            unsigned short* wT    = (unsigned short*)(base + wt_off);
            k_f2b<<<2048, 256, 0, stream>>>(feat, featb, (long)N * D / 8);
            k_wT<<<D, 256, 0, stream>>>(W, wT);
            k_fillcap<<<2048, 256, 0, stream>>>(src, dst, counts, buckets, ovf, ovf_cnt, E);
            g_bf_out<<<gat_blocks, 256, 0, stream>>>(featb, counts, buckets, ovf, ovf_cnt, out, N);
            gemm_mfma<<<gemm_blocks, 256, 0, stream>>>(wT, out, N);
        } else {
            // wT aliases buckets (dead after gather)
            unsigned short* wT = (unsigned short*)(((uintptr_t)buckets + 255) & ~(uintptr_t)255);
            k_fillcap<<<2048, 256, 0, stream>>>(src, dst, counts, buckets, ovf, ovf_cnt, E);
            g_f32_out<<<gat_blocks, 256, 0, stream>>>(feat, counts, buckets, ovf, ovf_cnt, out, N);
            k_wT<<<D, 256, 0, stream>>>(W, wT);
            gemm_mfma<<<gemm_blocks, 256, 0, stream>>>(wT, out, N);
        }
    } else if (ws_size >= need_csr) {
        int* counts  = (int*)d_ws;
        int* offsets = counts + N;
        int* cursor  = offsets + N + 1;
        int* buckets = cursor + N;

        k_zero<<<(N + 255) / 256, 256, 0, stream>>>(counts, N);
        k_hist<<<2048, 256, 0, stream>>>(dst, counts, E);
        k_scan<<<1, SCAN_THREADS, 0, stream>>>(counts, offsets, cursor, N);
        k_fill<<<2048, 256, 0, stream>>>(src, dst, cursor, buckets, E);
        k_gather_csr<<<gat_blocks, 256, 0, stream>>>(feat, offsets, buckets, out, N);
        unsigned short* wT =
            (unsigned short*)(((uintptr_t)buckets + 255) & ~(uintptr_t)255);
        k_wT<<<D, 256, 0, stream>>>(W, wT);
        gemm_mfma<<<gemm_blocks, 256, 0, stream>>>(wT, out, N);
    } else {
        long n4 = (long)N * D / 4;
        gc_copy<<<(int)((n4 + 255) / 256), 256, 0, stream>>>(feat, out, n4);
        gc_scatter<<<(E + 3) / 4, 256, 0, stream>>>(feat, src, dst, out, E);
        gemm_relu<<<(N + 31) / 32, 256, 0, stream>>>(W, out, N);
    }
}

// Round 7
// 298.302 us; speedup vs baseline: 19.0988x; 1.3443x over previous
//
#include <hip/hip_runtime.h>

#define D 256
#define SCAN_THREADS 1024
#define CAP 32
#define MAXOVF 4096
#define BM 64

typedef float f32x4 __attribute__((ext_vector_type(4)));
typedef short s16x8 __attribute__((ext_vector_type(8)));

__device__ inline unsigned int f2bf(float x) {
    unsigned int u = __float_as_uint(x);
    return (u + 0x7FFFu + ((u >> 16) & 1u)) >> 16;  // RNE, low 16 bits valid
}
__device__ inline float bflo(unsigned int u) { return __uint_as_float(u << 16); }
__device__ inline float bfhi(unsigned int u) { return __uint_as_float(u & 0xFFFF0000u); }

// ================= small utility kernels =================

__global__ void k_zero(int* __restrict__ p, int n) {
    int i = blockIdx.x * blockDim.x + threadIdx.x;
    if (i < n) p[i] = 0;
}

// feat fp32 -> bf16 (packed), 8 elems/thread
__global__ __launch_bounds__(256) void k_f2b(const float* __restrict__ f,
                                             unsigned short* __restrict__ fb, long n8) {
    for (long i = blockIdx.x * 256L + threadIdx.x; i < n8; i += (long)gridDim.x * 256) {
        const float4* p = reinterpret_cast<const float4*>(f + i * 8);
        float4 a = p[0], b = p[1];
        uint4 u;
        u.x = f2bf(a.x) | (f2bf(a.y) << 16);
        u.y = f2bf(a.z) | (f2bf(a.w) << 16);
        u.z = f2bf(b.x) | (f2bf(b.y) << 16);
        u.w = f2bf(b.z) | (f2bf(b.w) << 16);
        reinterpret_cast<uint4*>(fb)[i] = u;
    }
}

// W[k][col] fp32 -> wTs: per-ks staged-B LDS image (8 blocks x 16KB).
// Within block ks: byte = (col*64 + ((k>>3)&3)*16 + (k&7)*2) ^ ((col&7)<<4)
__global__ __launch_bounds__(256) void k_wTs(const float* __restrict__ W,
                                             unsigned short* __restrict__ wTs) {
    int col = blockIdx.x;   // 0..255
    int k = threadIdx.x;    // 0..255
    unsigned short v = (unsigned short)f2bf(W[(size_t)k * D + col]);
    int ks = k >> 5;
    int byte = ((col << 6) + (((k >> 3) & 3) << 4) + ((k & 7) << 1)) ^ ((col & 7) << 4);
    *reinterpret_cast<unsigned short*>(
        reinterpret_cast<char*>(wTs) + (size_t)ks * 16384 + byte) = v;
}

// ================= capacity-bucket build =================

__global__ void k_fillcap(const int* __restrict__ src, const int* __restrict__ dst,
                          int* __restrict__ counts, int* __restrict__ buckets,
                          int* __restrict__ ovf, int* __restrict__ ovf_cnt, int E) {
    for (int e = blockIdx.x * blockDim.x + threadIdx.x; e < E;
         e += gridDim.x * blockDim.x) {
        int d = dst[e];
        int pos = atomicAdd(&counts[d], 1);
        if (pos < CAP) {
            buckets[(size_t)d * CAP + pos] = src[e];
        } else {
            int o = atomicAdd(ovf_cnt, 1);
            if (o < MAXOVF) {
                ovf[2 * o + 0] = src[e];
                ovf[2 * o + 1] = d;
            }
        }
    }
}

// ================= gathers (one wave per node) =================

#define GAT_BODY(LOAD, ACCUM)                                                  \
    int j = 0;                                                                 \
    for (; j + 16 <= cnt; j += 16) {                                           \
        int s[16];                                                             \
        _Pragma("unroll") for (int q = 0; q < 16; ++q) s[q] = bk[j + q];       \
        LOAD(16)                                                               \
        ACCUM(16)                                                              \
    }                                                                          \
    for (; j + 8 <= cnt; j += 8) {                                             \
        int s[8];                                                              \
        _Pragma("unroll") for (int q = 0; q < 8; ++q) s[q] = bk[j + q];        \
        LOAD(8)                                                                \
        ACCUM(8)                                                               \
    }

// Tier A: bf16 feat reads, fp32 accum, swizzled bf16 agg write to ws.
__global__ __launch_bounds__(256) void g_bf_aggb(const unsigned short* __restrict__ fb,
                                                 const int* __restrict__ counts,
                                                 const int* __restrict__ buckets,
                                                 const int* __restrict__ ovf,
                                                 const int* __restrict__ ovf_cnt,
                                                 unsigned short* __restrict__ aggb, int N) {
    int node = (int)((blockIdx.x * (long)blockDim.x + threadIdx.x) >> 6);
    int ln = threadIdx.x & 63;
    if (node >= N) return;
    int cnt_raw = counts[node];
    int cnt = cnt_raw > CAP ? CAP : cnt_raw;
    const int* bk = buckets + (size_t)node * CAP;
    uint2 u = reinterpret_cast<const uint2*>(fb + (size_t)node * D)[ln];
    float4 acc;
    acc.x = bflo(u.x); acc.y = bfhi(u.x); acc.z = bflo(u.y); acc.w = bfhi(u.y);
#define BLOAD(W_)                                                              \
    uint2 v[W_];                                                               \
    _Pragma("unroll") for (int q = 0; q < W_; ++q)                             \
        v[q] = reinterpret_cast<const uint2*>(fb + (size_t)s[q] * D)[ln];
#define BACC(W_)                                                               \
    _Pragma("unroll") for (int q = 0; q < W_; ++q) {                           \
        acc.x += bflo(v[q].x); acc.y += bfhi(v[q].x);                          \
        acc.z += bflo(v[q].y); acc.w += bfhi(v[q].y);                          \
    }
    GAT_BODY(BLOAD, BACC)
    for (; j < cnt; ++j) {
        uint2 v = reinterpret_cast<const uint2*>(fb + (size_t)bk[j] * D)[ln];
        acc.x += bflo(v.x); acc.y += bfhi(v.x);
        acc.z += bflo(v.y); acc.w += bfhi(v.y);
    }
    if (cnt_raw > CAP) {  // astronomically rare; exact cleanup
        int m = *ovf_cnt;
        if (m > MAXOVF) m = MAXOVF;
        for (int e = 0; e < m; ++e) {
            if (ovf[2 * e + 1] == node) {
                uint2 v = reinterpret_cast<const uint2*>(fb + (size_t)ovf[2 * e] * D)[ln];
                acc.x += bflo(v.x); acc.y += bfhi(v.x);
                acc.z += bflo(v.y); acc.w += bfhi(v.y);
            }
        }
    }
    uint2 w;
    w.x = f2bf(acc.x) | (f2bf(acc.y) << 16);
    w.y = f2bf(acc.z) | (f2bf(acc.w) << 16);
    unsigned short* rowp = aggb + (size_t)node * D;
    int us = (ln * 4) ^ ((node & 7) << 3);
    *reinterpret_cast<uint2*>(rowp + us) = w;
}

// Tier B: bf16 feat reads, fp32 agg write to d_out.
__global__ __launch_bounds__(256) void g_bf_out(const unsigned short* __restrict__ fb,
                                                const int* __restrict__ counts,
                                                const int* __restrict__ buckets,
                                                const int* __restrict__ ovf,
                                                const int* __restrict__ ovf_cnt,
                                                float* __restrict__ out, int N) {
    int node = (int)((blockIdx.x * (long)blockDim.x + threadIdx.x) >> 6);
    int ln = threadIdx.x & 63;
    if (node >= N) return;
    int cnt_raw = counts[node];
    int cnt = cnt_raw > CAP ? CAP : cnt_raw;
    const int* bk = buckets + (size_t)node * CAP;
    uint2 u = reinterpret_cast<const uint2*>(fb + (size_t)node * D)[ln];
    float4 acc;
    acc.x = bflo(u.x); acc.y = bfhi(u.x); acc.z = bflo(u.y); acc.w = bfhi(u.y);
    GAT_BODY(BLOAD, BACC)
    for (; j < cnt; ++j) {
        uint2 v = reinterpret_cast<const uint2*>(fb + (size_t)bk[j] * D)[ln];
        acc.x += bflo(v.x); acc.y += bfhi(v.x);
        acc.z += bflo(v.y); acc.w += bfhi(v.y);
    }
    if (cnt_raw > CAP) {
        int m = *ovf_cnt;
        if (m > MAXOVF) m = MAXOVF;
        for (int e = 0; e < m; ++e) {
            if (ovf[2 * e + 1] == node) {
                uint2 v = reinterpret_cast<const uint2*>(fb + (size_t)ovf[2 * e] * D)[ln];
                acc.x += bflo(v.x); acc.y += bfhi(v.x);
                acc.z += bflo(v.y); acc.w += bfhi(v.y);
            }
        }
    }
    reinterpret_cast<float4*>(out + (size_t)node * D)[ln] = acc;
}

// Tier C: fp32 feat reads, fp32 agg write to d_out.
__global__ __launch_bounds__(256) void g_f32_out(const float* __restrict__ feat,
                                                 const int* __restrict__ counts,
                                                 const int* __restrict__ buckets,
                                                 const int* __restrict__ ovf,
                                                 const int* __restrict__ ovf_cnt,
                                                 float* __restrict__ out, int N) {
    int node = (int)((blockIdx.x * (long)blockDim.x + threadIdx.x) >> 6);
    int ln = threadIdx.x & 63;
    if (node >= N) return;
    int cnt_raw = counts[node];
    int cnt = cnt_raw > CAP ? CAP : cnt_raw;
    const int* bk = buckets + (size_t)node * CAP;
    float4 acc = reinterpret_cast<const float4*>(feat + (size_t)node * D)[ln];
#define FLOAD(W_)                                                              \
    float4 v[W_];                                                              \
    _Pragma("unroll") for (int q = 0; q < W_; ++q)                             \
        v[q] = reinterpret_cast<const float4*>(feat + (size_t)s[q] * D)[ln];
#define FACC(W_)                                                               \
    _Pragma("unroll") for (int q = 0; q < W_; ++q) {                           \
        acc.x += v[q].x; acc.y += v[q].y; acc.z += v[q].z; acc.w += v[q].w;    \
    }
    GAT_BODY(FLOAD, FACC)
    for (; j < cnt; ++j) {
        float4 v = reinterpret_cast<const float4*>(feat + (size_t)bk[j] * D)[ln];
        acc.x += v.x; acc.y += v.y; acc.z += v.z; acc.w += v.w;
    }
    if (cnt_raw > CAP) {
        int m = *ovf_cnt;
        if (m > MAXOVF) m = MAXOVF;
        for (int e = 0; e < m; ++e) {
            if (ovf[2 * e + 1] == node) {
                float4 v = reinterpret_cast<const float4*>(feat + (size_t)ovf[2 * e] * D)[ln];
                acc.x += v.x; acc.y += v.y; acc.z += v.z; acc.w += v.w;
            }
        }
    }
    reinterpret_cast<float4*>(out + (size_t)node * D)[ln] = acc;
}

// ================= CSR build (fallback path) =================

__global__ void k_hist(const int* __restrict__ dst, int* __restrict__ counts, int E) {
    for (int e = blockIdx.x * blockDim.x + threadIdx.x; e < E;
         e += gridDim.x * blockDim.x)
        atomicAdd(&counts[dst[e]], 1);
}

__global__ __launch_bounds__(SCAN_THREADS) void k_scan(const int* __restrict__ counts,
                                                       int* __restrict__ offsets,
                                                       int* __restrict__ cursor,
                                                       int N) {
    __shared__ int s[SCAN_THREADS];
    const int t = threadIdx.x;
    const int chunk = (N + SCAN_THREADS - 1) / SCAN_THREADS;
    const int lo = t * chunk;
    const int hi = min(N, lo + chunk);
    int local = 0;
    for (int i = lo; i < hi; ++i) local += counts[i];
    s[t] = local;
    __syncthreads();
    for (int str = 1; str < SCAN_THREADS; str <<= 1) {
        int v = (t >= str) ? s[t - str] : 0;
        __syncthreads();
        s[t] += v;
        __syncthreads();
    }
    int run = s[t] - local;
    for (int i = lo; i < hi; ++i) {
        offsets[i] = run;
        cursor[i] = run;
        run += counts[i];
    }
    if (t == SCAN_THREADS - 1) offsets[N] = s[SCAN_THREADS - 1];
}

__global__ void k_fill(const int* __restrict__ src, const int* __restrict__ dst,
                       int* __restrict__ cursor, int* __restrict__ buckets, int E) {
    for (int e = blockIdx.x * blockDim.x + threadIdx.x; e < E;
         e += gridDim.x * blockDim.x) {
        int pos = atomicAdd(&cursor[dst[e]], 1);
        buckets[pos] = src[e];
    }
}

__global__ __launch_bounds__(256) void k_gather_csr(const float* __restrict__ feat,
                                                    const int* __restrict__ offsets,
                                                    const int* __restrict__ buckets,
                                                    float* __restrict__ out, int N) {
    int wave = (int)((blockIdx.x * (long)blockDim.x + threadIdx.x) >> 6);
    int lane = threadIdx.x & 63;
    if (wave >= N) return;
    const int off = offsets[wave];
    const int end = offsets[wave + 1];
    float4 acc = reinterpret_cast<const float4*>(feat + (size_t)wave * D)[lane];
    int j = off;
    for (; j + 8 <= end; j += 8) {
        int s[8];
        #pragma unroll
        for (int q = 0; q < 8; ++q) s[q] = buckets[j + q];
        float4 v[8];
        #pragma unroll
        for (int q = 0; q < 8; ++q)
            v[q] = reinterpret_cast<const float4*>(feat + (size_t)s[q] * D)[lane];
        #pragma unroll
        for (int q = 0; q < 8; ++q) {
            acc.x += v[q].x; acc.y += v[q].y; acc.z += v[q].z; acc.w += v[q].w;
        }
    }
    for (; j < end; ++j) {
        float4 v = reinterpret_cast<const float4*>(feat + (size_t)buckets[j] * D)[lane];
        acc.x += v.x; acc.y += v.y; acc.z += v.z; acc.w += v.w;
    }
    reinterpret_cast<float4*>(out + (size_t)wave * D)[lane] = acc;
}

// ================= atomic scatter (last-resort) =================

__global__ __launch_bounds__(256) void gc_copy(const float* __restrict__ feat,
                                               float* __restrict__ agg, long n4) {
    long i = (long)blockIdx.x * blockDim.x + threadIdx.x;
    if (i < n4)
        reinterpret_cast<float4*>(agg)[i] = reinterpret_cast<const float4*>(feat)[i];
}

__global__ __launch_bounds__(256) void gc_scatter(const float* __restrict__ feat,
                                                  const int* __restrict__ src,
                                                  const int* __restrict__ dst,
                                                  float* __restrict__ agg, int n_edges) {
    int wave = (int)((blockIdx.x * (long)blockDim.x + threadIdx.x) >> 6);
    int lane = threadIdx.x & 63;
    if (wave >= n_edges) return;
    int s = src[wave];
    int d = dst[wave];
    const float4 v = reinterpret_cast<const float4*>(feat + (size_t)s * D)[lane];
    float* p = agg + (size_t)d * D + (size_t)lane * 4;
    atomicAdd(p + 0, v.x);
    atomicAdd(p + 1, v.y);
    atomicAdd(p + 2, v.z);
    atomicAdd(p + 3, v.w);
}

// ================= MFMA GEMMs (B staged per-ks into LDS) =================

__device__ inline void gload16(const char* g, const unsigned char* lds) {
    __builtin_amdgcn_global_load_lds(
        (const __attribute__((address_space(1))) void*)g,
        (__attribute__((address_space(3))) void*)lds, 16, 0, 0);
}

// Shared compute: A image in s_a (32KB), B staged per ks from wTs into s_b.
// Tier A: A staged via global_load_lds from swizzled bf16 agg in ws.
__global__ __launch_bounds__(256) void gemm_mfma_b(const unsigned short* __restrict__ aggb,
                                                   const unsigned short* __restrict__ wTs,
                                                   float* __restrict__ out, int n_rows) {
    __shared__ __align__(16) unsigned char s_a[BM * 512];  // 64 rows x 256 bf16
    __shared__ __align__(16) unsigned char s_b[16384];     // one ks-slice of B
    const int t = threadIdx.x;
    const int row0 = blockIdx.x * BM;
    const int wv = t >> 6;
    const int l = t & 63;
    const char* wb = reinterpret_cast<const char*>(wTs);

    // prologue: stage A (8 x 1KB per wave) + B(ks=0) (1 x 1KB per wave x4)
    const char* gbase = reinterpret_cast<const char*>(aggb) + (size_t)row0 * 512;
    #pragma unroll
    for (int q = 0; q < 8; ++q) {
        int off = wv * 8192 + q * 1024;
        gload16(gbase + off + l * 16, s_a + off);
    }
    #pragma unroll
    for (int i = 0; i < 4; ++i) {
        int off = wv * 4096 + i * 1024;
        gload16(wb + off + l * 16, s_b + off);
    }
    __syncthreads();

    f32x4 acc[16];
    #pragma unroll
    for (int ct = 0; ct < 16; ++ct) acc[ct] = (f32x4){0.f, 0.f, 0.f, 0.f};

    const int lr = wv * 16 + (l & 15);
    const int g = l >> 4;
    for (int ks = 0; ks < 8; ++ks) {
        const int kb = ks * 32 + g * 8;
        const int ab = (lr * 512 + kb * 2) ^ ((lr & 7) << 4);
        s16x8 af = *reinterpret_cast<const s16x8*>(s_a + ab);
        #pragma unroll
        for (int ct = 0; ct < 16; ++ct) {
            int col = ct * 16 + (l & 15);
            int bb = (col * 64 + g * 16) ^ ((col & 7) << 4);
            s16x8 bf = *reinterpret_cast<const s16x8*>(s_b + bb);
            acc[ct] = __builtin_amdgcn_mfma_f32_16x16x32_bf16(af, bf, acc[ct], 0, 0, 0);
        }
        __syncthreads();  // all waves done reading s_b
        if (ks < 7) {
            #pragma unroll
            for (int i = 0; i < 4; ++i) {
                int off = wv * 4096 + i * 1024;
                gload16(wb + (size_t)(ks + 1) * 16384 + off + l * 16, s_b + off);
            }
            __syncthreads();
        }
    }

    const int rbase = row0 + wv * 16 + (l >> 4) * 4;
    const int cb = l & 15;
    #pragma unroll
    for (int ct = 0; ct < 16; ++ct) {
        #pragma unroll
        for (int r = 0; r < 4; ++r) {
            int row = rbase + r;
            if (row < n_rows)
                out[(size_t)row * D + ct * 16 + cb] = fmaxf(acc[ct][r], 0.f);
        }
    }
}

// Tiers B/C/CSR: A read fp32 from out (in-place), converted + swizzled reg->LDS.
__global__ __launch_bounds__(256) void gemm_mfma(const unsigned short* __restrict__ wTs,
                                                 float* __restrict__ out, int n_rows) {
    __shared__ __align__(16) unsigned char s_a[BM * 512];
    __shared__ __align__(16) unsigned char s_b[16384];
    const int t = threadIdx.x;
    const int row0 = blockIdx.x * BM;
    const int wv = t >> 6;
    const int l = t & 63;
    const char* wb = reinterpret_cast<const char*>(wTs);

    #pragma unroll
    for (int i = 0; i < 4; ++i) {
        int off = wv * 4096 + i * 1024;
        gload16(wb + off + l * 16, s_b + off);
    }
    #pragma unroll
    for (int i = 0; i < 16; ++i) {
        int f4 = t + 256 * i;
        int row = f4 >> 6;
        int kc = f4 & 63;
        int grow = row0 + row;
        if (grow >= n_rows) grow = n_rows - 1;
        float4 v = *reinterpret_cast<const float4*>(out + (size_t)grow * D + kc * 4);
        uint2 u;
        u.x = f2bf(v.x) | (f2bf(v.y) << 16);
        u.y = f2bf(v.z) | (f2bf(v.w) << 16);
        int byte = (row * 512 + kc * 8) ^ ((row & 7) << 4);
        *reinterpret_cast<uint2*>(s_a + byte) = u;
    }
    __syncthreads();

    f32x4 acc[16];
    #pragma unroll
    for (int ct = 0; ct < 16; ++ct) acc[ct] = (f32x4){0.f, 0.f, 0.f, 0.f};

    const int lr = wv * 16 + (l & 15);
    const int g = l >> 4;
    for (int ks = 0; ks < 8; ++ks) {
        const int kb = ks * 32 + g * 8;
        const int ab = (lr * 512 + kb * 2) ^ ((lr & 7) << 4);
        s16x8 af = *reinterpret_cast<const s16x8*>(s_a + ab);
        #pragma unroll
        for (int ct = 0; ct < 16; ++ct) {
            int col = ct * 16 + (l & 15);
            int bb = (col * 64 + g * 16) ^ ((col & 7) << 4);
            s16x8 bf = *reinterpret_cast<const s16x8*>(s_b + bb);
            acc[ct] = __builtin_amdgcn_mfma_f32_16x16x32_bf16(af, bf, acc[ct], 0, 0, 0);
        }
        __syncthreads();
        if (ks < 7) {
            #pragma unroll
            for (int i = 0; i < 4; ++i) {
                int off = wv * 4096 + i * 1024;
                gload16(wb + (size_t)(ks + 1) * 16384 + off + l * 16, s_b + off);
            }
            __syncthreads();
        }
    }

    const int rbase = row0 + wv * 16 + (l >> 4) * 4;
    const int cb = l & 15;
    #pragma unroll
    for (int ct = 0; ct < 16; ++ct) {
        #pragma unroll
        for (int r = 0; r < 4; ++r) {
            int row = rbase + r;
            if (row < n_rows)
                out[(size_t)row * D + ct * 16 + cb] = fmaxf(acc[ct][r], 0.f);
        }
    }
}

// legacy fp32 GEMM (no-workspace fallback)
__global__ __launch_bounds__(256) void gemm_relu(const float* __restrict__ Wm,
                                                 float* __restrict__ out, int n_rows) {
    __shared__ float s_a[32][D];
    const int row0 = blockIdx.x * 32;
    const int c = threadIdx.x;
    {
        const float4* gsrc = reinterpret_cast<const float4*>(out + (size_t)row0 * D);
        float4* ldst = reinterpret_cast<float4*>(&s_a[0][0]);
        #pragma unroll
        for (int i = 0; i < 8; ++i)
            ldst[threadIdx.x + i * 256] = gsrc[threadIdx.x + i * 256];
    }
    __syncthreads();
    float acc[32];
    #pragma unroll
    for (int r = 0; r < 32; ++r) acc[r] = 0.f;
    #pragma unroll 4
    for (int k = 0; k < D; ++k) {
        float w = Wm[(size_t)k * D + c];
        #pragma unroll
        for (int r = 0; r < 32; ++r) acc[r] += s_a[r][k] * w;
    }
    #pragma unroll
    for (int r = 0; r < 32; ++r) {
        int row = row0 + r;
        if (row < n_rows) out[(size_t)row * D + c] = fmaxf(acc[r], 0.f);
    }
}

extern "C" void kernel_launch(void* const* d_in, const int* in_sizes, int n_in,
                              void* d_out, int out_size, void* d_ws, size_t ws_size,
                              hipStream_t stream) {
    const float* feat = (const float*)d_in[0];
    const float* W    = (const float*)d_in[1];
    const int*   src  = (const int*)d_in[2];
    const int*   dst  = (const int*)d_in[3];
    float* out = (float*)d_out;

    const int N = in_sizes[0] / D;  // 100000
    const int E = in_sizes[2];      // 1600000
    const int Npad = ((N + BM - 1) / BM) * BM;
    auto al = [](size_t x) { return (x + 255) & ~(size_t)255; };

    // cap structures: counts[N] | ovf_cnt[1] | ovf[2*MAXOVF] | buckets[N*CAP]
    const size_t cap_bytes = ((size_t)N + 1 + 2 * MAXOVF + (size_t)N * CAP) * 4;
    const size_t featb_off = al(cap_bytes);
    const size_t featb_sz  = (size_t)N * D * 2;
    const size_t wt_off    = al(featb_off + featb_sz);
    const size_t wt_sz     = (size_t)D * D * 2;   // wTs: 8 x 16KB
    const size_t aggb_off  = al(wt_off + wt_sz);
    const size_t aggb_sz   = (size_t)Npad * D * 2;

    const size_t need_A   = aggb_off + aggb_sz;
    const size_t need_B   = wt_off + wt_sz;
    const size_t need_C   = cap_bytes;            // wTs aliases buckets
    const size_t need_csr = ((size_t)3 * N + 1 + (size_t)E) * 4;

    const int gemm_blocks = (N + BM - 1) / BM;
    const int gat_blocks = (N + 3) / 4;

    if (ws_size >= need_C) {
        char* base = (char*)d_ws;
        int* counts  = (int*)base;
        int* ovf_cnt = counts + N;
        int* ovf     = ovf_cnt + 1;
        int* buckets = ovf + 2 * MAXOVF;

        k_zero<<<(N + 1 + 255) / 256, 256, 0, stream>>>(counts, N + 1);

        if (ws_size >= need_A) {
            unsigned short* featb = (unsigned short*)(base + featb_off);
            unsigned short* wTs   = (unsigned short*)(base + wt_off);
            unsigned short* aggb  = (unsigned short*)(base + aggb_off);
            k_f2b<<<2048, 256, 0, stream>>>(feat, featb, (long)N * D / 8);
            k_wTs<<<D, 256, 0, stream>>>(W, wTs);
            k_fillcap<<<2048, 256, 0, stream>>>(src, dst, counts, buckets, ovf, ovf_cnt, E);
            g_bf_aggb<<<gat_blocks, 256, 0, stream>>>(featb, counts, buckets, ovf, ovf_cnt, aggb, N);
            gemm_mfma_b<<<gemm_blocks, 256, 0, stream>>>(aggb, wTs, out, N);
        } else if (ws_size >= need_B) {
            unsigned short* featb = (unsigned short*)(base + featb_off);
            unsigned short* wTs   = (unsigned short*)(base + wt_off);
            k_f2b<<<2048, 256, 0, stream>>>(feat, featb, (long)N * D / 8);
            k_wTs<<<D, 256, 0, stream>>>(W, wTs);
            k_fillcap<<<2048, 256, 0, stream>>>(src, dst, counts, buckets, ovf, ovf_cnt, E);
            g_bf_out<<<gat_blocks, 256, 0, stream>>>(featb, counts, buckets, ovf, ovf_cnt, out, N);
            gemm_mfma<<<gemm_blocks, 256, 0, stream>>>(wTs, out, N);
        } else {
            unsigned short* wTs = (unsigned short*)(((uintptr_t)buckets + 255) & ~(uintptr_t)255);
            k_fillcap<<<2048, 256, 0, stream>>>(src, dst, counts, buckets, ovf, ovf_cnt, E);
            g_f32_out<<<gat_blocks, 256, 0, stream>>>(feat, counts, buckets, ovf, ovf_cnt, out, N);
            k_wTs<<<D, 256, 0, stream>>>(W, wTs);
            gemm_mfma<<<gemm_blocks, 256, 0, stream>>>(wTs, out, N);
        }
    } else if (ws_size >= need_csr) {
        int* counts  = (int*)d_ws;
        int* offsets = counts + N;
        int* cursor  = offsets + N + 1;
        int* buckets = cursor + N;

        k_zero<<<(N + 255) / 256, 256, 0, stream>>>(counts, N);
        k_hist<<<2048, 256, 0, stream>>>(dst, counts, E);
        k_scan<<<1, SCAN_THREADS, 0, stream>>>(counts, offsets, cursor, N);
        k_fill<<<2048, 256, 0, stream>>>(src, dst, cursor, buckets, E);
        k_gather_csr<<<gat_blocks, 256, 0, stream>>>(feat, offsets, buckets, out, N);
        unsigned short* wTs =
            (unsigned short*)(((uintptr_t)buckets + 255) & ~(uintptr_t)255);
        k_wTs<<<D, 256, 0, stream>>>(W, wTs);
        gemm_mfma<<<gemm_blocks, 256, 0, stream>>>(wTs, out, N);
    } else {
        long n4 = (long)N * D / 4;
        gc_copy<<<(int)((n4 + 255) / 256), 256, 0, stream>>>(feat, out, n4);
        gc_scatter<<<(E + 3) / 4, 256, 0, stream>>>(feat, src, dst, out, E);
        gemm_relu<<<(N + 31) / 32, 256, 0, stream>>>(W, out, N);
    }
}